// Round 14
// baseline (666.880 us; speedup 1.0000x reference)
//
#include <hip/hip_runtime.h>
#include <hip/hip_bf16.h>
#include <cstdint>
#include <cstddef>

#define B_SZ   4
#define N_PTS  2048
#define KNN    20
#define BN_ROWS (B_SZ * N_PTS)
#define EPSV   1e-5f
#define SLOPEV 0.2f

#define MODE_GD   0
#define MODE_DIST 1

typedef __attribute__((ext_vector_type(8))) short bf16x8;
typedef __attribute__((ext_vector_type(4))) float f32x4;

// ---------------------------------------------------------------- DPP wave reductions
// Canonical GCN 64-lane reduce: row_shr 1/2/4/8 + row_bcast:15 (rows 1,3) +
// row_bcast:31 (rows 2,3), result in lane 63. VALU-pipe only (the previous
// __shfl_xor butterfly compiled to ds_bpermute: LDS pipe + 6-deep latency chain
// per bisection iteration — the measured k_select bottleneck).
__device__ __forceinline__ int wred_add(int v)
{
    v += __builtin_amdgcn_update_dpp(0, v, 0x111, 0xf, 0xf, false);
    v += __builtin_amdgcn_update_dpp(0, v, 0x112, 0xf, 0xf, false);
    v += __builtin_amdgcn_update_dpp(0, v, 0x114, 0xf, 0xf, false);
    v += __builtin_amdgcn_update_dpp(0, v, 0x118, 0xf, 0xf, false);
    v += __builtin_amdgcn_update_dpp(0, v, 0x142, 0xa, 0xf, false);
    v += __builtin_amdgcn_update_dpp(0, v, 0x143, 0xc, 0xf, false);
    return __builtin_amdgcn_readlane(v, 63);
}
__device__ __forceinline__ unsigned wred_umax(unsigned v)
{
    unsigned t;
    t = (unsigned)__builtin_amdgcn_update_dpp(0, (int)v, 0x111, 0xf, 0xf, false); v = v > t ? v : t;
    t = (unsigned)__builtin_amdgcn_update_dpp(0, (int)v, 0x112, 0xf, 0xf, false); v = v > t ? v : t;
    t = (unsigned)__builtin_amdgcn_update_dpp(0, (int)v, 0x114, 0xf, 0xf, false); v = v > t ? v : t;
    t = (unsigned)__builtin_amdgcn_update_dpp(0, (int)v, 0x118, 0xf, 0xf, false); v = v > t ? v : t;
    t = (unsigned)__builtin_amdgcn_update_dpp(0, (int)v, 0x142, 0xa, 0xf, false); v = v > t ? v : t;
    t = (unsigned)__builtin_amdgcn_update_dpp(0, (int)v, 0x143, 0xc, 0xf, false); v = v > t ? v : t;
    return (unsigned)__builtin_amdgcn_readlane((int)v, 63);
}
__device__ __forceinline__ unsigned wred_umin(unsigned v)
{
    unsigned t;
    t = (unsigned)__builtin_amdgcn_update_dpp(-1, (int)v, 0x111, 0xf, 0xf, false); v = v < t ? v : t;
    t = (unsigned)__builtin_amdgcn_update_dpp(-1, (int)v, 0x112, 0xf, 0xf, false); v = v < t ? v : t;
    t = (unsigned)__builtin_amdgcn_update_dpp(-1, (int)v, 0x114, 0xf, 0xf, false); v = v < t ? v : t;
    t = (unsigned)__builtin_amdgcn_update_dpp(-1, (int)v, 0x118, 0xf, 0xf, false); v = v < t ? v : t;
    t = (unsigned)__builtin_amdgcn_update_dpp(-1, (int)v, 0x142, 0xa, 0xf, false); v = v < t ? v : t;
    t = (unsigned)__builtin_amdgcn_update_dpp(-1, (int)v, 0x143, 0xc, 0xf, false); v = v < t ? v : t;
    return (unsigned)__builtin_amdgcn_readlane((int)v, 63);
}

// ---------------------------------------------------------------- transpose + xx
__global__ void k_transpose(const float* __restrict__ x, float* __restrict__ xt,
                            float* __restrict__ xx)
{
    int i = blockIdx.x * 256 + threadIdx.x;
    if (i >= BN_ROWS) return;
    int b = i >> 11, n = i & 2047;
    float v0 = x[((b * 3 + 0) << 11) + n];
    float v1 = x[((b * 3 + 1) << 11) + n];
    float v2 = x[((b * 3 + 2) << 11) + n];
    xt[i * 3 + 0] = v0; xt[i * 3 + 1] = v1; xt[i * 3 + 2] = v2;
    xx[i] = fmaf(v0, v0, fmaf(v1, v1, v2 * v2));
}

// ---------------------------------------------------------------- batched weight prep
__global__ void k_prepw_all(const float* __restrict__ W1, const float* __restrict__ W2,
                            const float* __restrict__ W3, const float* __restrict__ W4,
                            const float* __restrict__ W5, const float* __restrict__ Wf,
                            float* __restrict__ wc, __hip_bfloat16* __restrict__ w5h,
                            float* __restrict__ wft)
{
    int i = blockIdx.x * 256 + threadIdx.x;
    if (i >= 876928) return;
    if (i >= 614784) {                      // Wf transpose
        int e = i - 614784;                 // e = o*1024 + f
        int o = e >> 10, f = e & 1023;
        wft[f * 256 + o] = Wf[e];
        return;
    }
    if (i >= 90496) {                       // W5 (1024x512) -> bf16
        int e = i - 90496;
        w5h[e] = __float2bfloat16(W5[e]);
        return;
    }
    const float* W; int O, C, off;
    if      (i < 384)   { W = W1; O = 64;  C = 3;   off = 0; }
    else if (i < 8576)  { W = W2; O = 64;  C = 64;  off = 384; }
    else if (i < 24960) { W = W3; O = 128; C = 64;  off = 8576; }
    else                { W = W4; O = 256; C = 128; off = 24960; }
    int e = i - off, j = e / C, c = e - j * C;
    float v;
    if (j < O) v = W[j * 2 * C + c];
    else { int jo = j - O; v = W[jo * 2 * C + C + c] - W[jo * 2 * C + c]; }
    wc[i] = v;
}

// ---------------------------------------------------------------- GEMM core
// MODE_GD  : 128x64 tile. C = A(MxK) @ Bm(NnxK)^T, grid (Nn/64, M/128).
// MODE_DIST: 128x128 SYMMETRIC tile, grid (136, 1, 4). Tile order: 120
//   off-diagonal pairs (it<jt) first, 16 diagonal tiles LAST (diagonals skip
//   the mirror epilogue — cheap tail blocks absorb the 544-on-256-CU
//   grid-quantization imbalance). Diagonal forced to exact 0; D2 bitwise
//   identical to previous rounds.
template<int MODE, bool VEC>
__launch_bounds__(256)
__global__ void k_mm128(const float* __restrict__ A, int lda,
                        const float* __restrict__ Bm, int ldb,
                        const float* __restrict__ xx, int b0,
                        float* __restrict__ C1, float* __restrict__ C2,
                        int Nn, int Kd)
{
    constexpr int LDA_ = 132;     // 128 + 4 pad
    constexpr int LDB_ = (MODE == MODE_DIST) ? 132 : 68;
    constexpr int SMEMF = 32 * LDA_ + 32 * LDB_;   // DIST: 8448, GD: 6400
    __shared__ float smem[SMEMF];
    float* As = smem;
    float* Bs = smem + 32 * LDA_;
    float* T  = smem;             // DIST mirror transpose: 64 x 132 = 8448 == SMEMF
    const int tid = threadIdx.x;
    const int tx  = tid & 15;
    const int ty  = tid >> 4;

    int m0, n0;
    if constexpr (MODE == MODE_DIST) {
        int t = blockIdx.x;
        int it, jt;
        if (t < 120) {                     // off-diagonal pairs first
            int i = 0;
            for (; i < 15; ++i) { int cnt = 15 - i; if (t < cnt) break; t -= cnt; }
            it = i; jt = i + 1 + t;
        } else {                           // 16 diagonal tiles last (no mirror)
            it = jt = t - 120;
        }
        m0 = it * 128;
        n0 = jt * 128;
    } else {
        m0 = blockIdx.y * 128;
        n0 = blockIdx.x * 64;
    }

    const float* Ab;
    const float* Bb;
    int ldbe;
    if constexpr (MODE == MODE_DIST) {
        const int b = b0 + blockIdx.z;
        Ab = A + (size_t)b * N_PTS * lda;
        Bb = Ab;
        ldbe = lda;
    } else {
        Ab = A; Bb = Bm; ldbe = ldb;
    }

    constexpr int NJH = (MODE == MODE_DIST) ? 2 : 1;
    float acc[2][NJH][4][4] = {};

    for (int k0 = 0; k0 < Kd; k0 += 32) {
        #pragma unroll
        for (int r = 0; r < 4; ++r) {            // A: 128 rows x 32 k
            int e = r * 256 + tid, row = e >> 3, kq = e & 7;
            if constexpr (VEC) {
                float4 v = *(const float4*)&Ab[(size_t)(m0 + row) * lda + k0 + kq * 4];
                As[(kq * 4 + 0) * LDA_ + row] = v.x;
                As[(kq * 4 + 1) * LDA_ + row] = v.y;
                As[(kq * 4 + 2) * LDA_ + row] = v.z;
                As[(kq * 4 + 3) * LDA_ + row] = v.w;
            } else {
                #pragma unroll
                for (int j = 0; j < 4; ++j) {
                    int kg = k0 + kq * 4 + j;
                    As[(kq * 4 + j) * LDA_ + row] =
                        (kg < Kd) ? Ab[(size_t)(m0 + row) * lda + kg] : 0.f;
                }
            }
        }
        constexpr int BR = (MODE == MODE_DIST) ? 4 : 2;
        #pragma unroll
        for (int r = 0; r < BR; ++r) {
            int e = r * 256 + tid, row = e >> 3, kq = e & 7;
            if constexpr (VEC) {
                float4 v = *(const float4*)&Bb[(size_t)(n0 + row) * ldbe + k0 + kq * 4];
                Bs[(kq * 4 + 0) * LDB_ + row] = v.x;
                Bs[(kq * 4 + 1) * LDB_ + row] = v.y;
                Bs[(kq * 4 + 2) * LDB_ + row] = v.z;
                Bs[(kq * 4 + 3) * LDB_ + row] = v.w;
            } else {
                #pragma unroll
                for (int j = 0; j < 4; ++j) {
                    int kg = k0 + kq * 4 + j;
                    Bs[(kq * 4 + j) * LDB_ + row] =
                        (kg < Kd) ? Bb[(size_t)(n0 + row) * ldbe + kg] : 0.f;
                }
            }
        }
        __syncthreads();

        int klen = Kd - k0; if (klen > 32) klen = 32;
        #pragma unroll 8
        for (int kk = 0; kk < klen; ++kk) {
            float4 a0 = *(const float4*)&As[kk * LDA_ + ty * 4];
            float4 a1 = *(const float4*)&As[kk * LDA_ + 64 + ty * 4];
            float av[2][4] = {{a0.x,a0.y,a0.z,a0.w},{a1.x,a1.y,a1.z,a1.w}};
            if constexpr (MODE == MODE_DIST) {
                float4 b0q = *(const float4*)&Bs[kk * LDB_ + tx * 4];
                float4 b1q = *(const float4*)&Bs[kk * LDB_ + 64 + tx * 4];
                float bw[2][4] = {{b0q.x,b0q.y,b0q.z,b0q.w},{b1q.x,b1q.y,b1q.z,b1q.w}};
                #pragma unroll
                for (int ih = 0; ih < 2; ++ih)
                    #pragma unroll
                    for (int jh = 0; jh < 2; ++jh)
                        #pragma unroll
                        for (int ii = 0; ii < 4; ++ii)
                            #pragma unroll
                            for (int jj = 0; jj < 4; ++jj)
                                acc[ih][jh][ii][jj] = fmaf(av[ih][ii], bw[jh][jj], acc[ih][jh][ii][jj]);
            } else {
                float4 bq = *(const float4*)&Bs[kk * LDB_ + tx * 4];
                float bw[4] = {bq.x, bq.y, bq.z, bq.w};
                #pragma unroll
                for (int ih = 0; ih < 2; ++ih)
                    #pragma unroll
                    for (int ii = 0; ii < 4; ++ii)
                        #pragma unroll
                        for (int jj = 0; jj < 4; ++jj)
                            acc[ih][0][ii][jj] = fmaf(av[ih][ii], bw[jj], acc[ih][0][ii][jj]);
            }
        }
        __syncthreads();
    }

    if constexpr (MODE == MODE_DIST) {
        const float* xxb = xx + (b0 + blockIdx.z) * N_PTS;
        float xj[2][4];
        #pragma unroll
        for (int jh = 0; jh < 2; ++jh) {
            float4 v = *(const float4*)&xxb[n0 + jh * 64 + tx * 4];
            xj[jh][0] = v.x; xj[jh][1] = v.y; xj[jh][2] = v.z; xj[jh][3] = v.w;
        }
        float xiv[2][4];
        #pragma unroll
        for (int ih = 0; ih < 2; ++ih)
            #pragma unroll
            for (int i = 0; i < 4; ++i)
                xiv[ih][i] = xxb[m0 + ih * 64 + ty * 4 + i];
        const bool diag = (m0 == n0);
        const size_t zoff = (size_t)blockIdx.z * N_PTS;

        #pragma unroll
        for (int ih = 0; ih < 2; ++ih)
            #pragma unroll
            for (int i = 0; i < 4; ++i) {
                int gi = m0 + ih * 64 + ty * 4 + i;
                float xi = xiv[ih][i];
                size_t base = (zoff + gi) * N_PTS;
                #pragma unroll
                for (int jh = 0; jh < 2; ++jh) {
                    int gj = n0 + jh * 64 + tx * 4;
                    float4 v;
                    v.x = 2.f * acc[ih][jh][i][0] - xi - xj[jh][0];
                    v.y = 2.f * acc[ih][jh][i][1] - xi - xj[jh][1];
                    v.z = 2.f * acc[ih][jh][i][2] - xi - xj[jh][2];
                    v.w = 2.f * acc[ih][jh][i][3] - xi - xj[jh][3];
                    if (diag) {
                        if (gi == gj + 0) v.x = 0.f;
                        if (gi == gj + 1) v.y = 0.f;
                        if (gi == gj + 2) v.z = 0.f;
                        if (gi == gj + 3) v.w = 0.f;
                    }
                    *(float4*)&C1[base + gj] = v;
                }
            }

        if (!diag) {
            #pragma unroll
            for (int jh = 0; jh < 2; ++jh) {
                #pragma unroll
                for (int c = 0; c < 4; ++c) {
                    float xjc = xj[jh][c];
                    #pragma unroll
                    for (int ih = 0; ih < 2; ++ih) {
                        float4 tv;
                        tv.x = 2.f * acc[ih][jh][0][c] - xjc - xiv[ih][0];
                        tv.y = 2.f * acc[ih][jh][1][c] - xjc - xiv[ih][1];
                        tv.z = 2.f * acc[ih][jh][2][c] - xjc - xiv[ih][2];
                        tv.w = 2.f * acc[ih][jh][3][c] - xjc - xiv[ih][3];
                        *(float4*)&T[(tx * 4 + c) * LDA_ + ih * 64 + ty * 4] = tv;
                    }
                }
                __syncthreads();
                #pragma unroll
                for (int r = 0; r < 8; ++r) {
                    int e = r * 256 + tid;
                    int jr = e >> 5, c4 = e & 31;
                    float4 tv = *(const float4*)&T[jr * LDA_ + c4 * 4];
                    *(float4*)&C1[(zoff + n0 + jh * 64 + jr) * N_PTS + m0 + c4 * 4] = tv;
                }
                __syncthreads();
            }
        }
    } else {  // MODE_GD
        const int Oo = Nn >> 1;
        #pragma unroll
        for (int ih = 0; ih < 2; ++ih)
            #pragma unroll
            for (int i = 0; i < 4; ++i) {
                int row = m0 + ih * 64 + ty * 4 + i;
                int colg = n0 + tx * 4;
                float4 v = make_float4(acc[ih][0][i][0], acc[ih][0][i][1],
                                       acc[ih][0][i][2], acc[ih][0][i][3]);
                if (colg < Oo) *(float4*)&C1[(size_t)row * Oo + colg] = v;
                else           *(float4*)&C2[(size_t)row * Oo + colg - Oo] = v;
            }
    }
}

// ---------------------------------------------------------------- bf16 MFMA GEMM (layer 5)
__launch_bounds__(256)
__global__ void k_gemm5(const unsigned short* __restrict__ Ah,
                        const unsigned short* __restrict__ Bh,
                        float* __restrict__ Cf,
                        float* __restrict__ ssum, float* __restrict__ ssumsq)
{
    constexpr int LDA = 72;
    __shared__ unsigned short As[128 * LDA];
    __shared__ unsigned short Bs[128 * LDA];
    const int tid  = threadIdx.x;
    const int lane = tid & 63;
    const int w    = tid >> 6;
    const int wr   = w >> 1, wcl = w & 1;
    const int quad = lane >> 4;
    const int l16  = lane & 15;
    const int m0 = blockIdx.y * 128;
    const int n0 = blockIdx.x * 128;

    f32x4 acc[4][4] = {};

    for (int k0 = 0; k0 < 512; k0 += 64) {
        #pragma unroll
        for (int r = 0; r < 4; ++r) {
            int e = r * 256 + tid, row = e >> 3, kq = e & 7;
            *(uint4*)&As[row * LDA + kq * 8] =
                *(const uint4*)&Ah[(size_t)(m0 + row) * 512 + k0 + kq * 8];
        }
        #pragma unroll
        for (int r = 0; r < 4; ++r) {
            int e = r * 256 + tid, row = e >> 3, kq = e & 7;
            *(uint4*)&Bs[row * LDA + kq * 8] =
                *(const uint4*)&Bh[(size_t)(n0 + row) * 512 + k0 + kq * 8];
        }
        __syncthreads();
        #pragma unroll
        for (int kk = 0; kk < 64; kk += 32) {
            bf16x8 af[4], bfr[4];
            #pragma unroll
            for (int i = 0; i < 4; ++i)
                af[i] = *(const bf16x8*)&As[(wr * 64 + i * 16 + l16) * LDA + kk + quad * 8];
            #pragma unroll
            for (int j = 0; j < 4; ++j)
                bfr[j] = *(const bf16x8*)&Bs[(wcl * 64 + j * 16 + l16) * LDA + kk + quad * 8];
            #pragma unroll
            for (int i = 0; i < 4; ++i)
                #pragma unroll
                for (int j = 0; j < 4; ++j)
                    acc[i][j] = __builtin_amdgcn_mfma_f32_16x16x32_bf16(af[i], bfr[j], acc[i][j], 0, 0, 0);
        }
        __syncthreads();
    }

    #pragma unroll
    for (int i = 0; i < 4; ++i) {
        int rbase = m0 + wr * 64 + i * 16 + quad * 4;
        #pragma unroll
        for (int j = 0; j < 4; ++j) {
            int col = n0 + wcl * 64 + j * 16 + l16;
            #pragma unroll
            for (int r = 0; r < 4; ++r)
                Cf[(size_t)(rbase + r) * 1024 + col] = acc[i][j][r];
        }
    }

    float* sredS = (float*)As;
    float* sredQ = (float*)Bs;
    #pragma unroll
    for (int j = 0; j < 4; ++j) {
        float s = 0.f, q = 0.f;
        #pragma unroll
        for (int i = 0; i < 4; ++i)
            #pragma unroll
            for (int r = 0; r < 4; ++r) {
                float v = acc[i][j][r];
                s += v; q = fmaf(v, v, q);
            }
        int coll = wcl * 64 + j * 16 + l16;
        int slot = wr * 4 + quad;
        sredS[coll * 8 + slot] = s;
        sredQ[coll * 8 + slot] = q;
    }
    __syncthreads();
    if (tid < 128) {
        float s = 0.f, q = 0.f;
        #pragma unroll
        for (int t = 0; t < 8; ++t) { s += sredS[tid * 8 + t]; q += sredQ[tid * 8 + t]; }
        ssum  [blockIdx.y * 1024 + n0 + tid] = s;
        ssumsq[blockIdx.y * 1024 + n0 + tid] = q;
    }
}

// ---------------------------------------------------------------- top-20 select (all 4 batches)
// DPP-reduce bisection with key-range-clamped bounds.
__launch_bounds__(256)
__global__ void k_select(const float* __restrict__ D2, int* __restrict__ idx_out)
{
    const int lane = threadIdx.x & 63;
    const int w    = threadIdx.x >> 6;
    const int qloc = blockIdx.x * 4 + w;          // 0..8191
    const float* row = D2 + (size_t)qloc * N_PTS;

    unsigned key[32];
    unsigned kmin = 0xFFFFFFFFu, kmax = 0u;
    #pragma unroll
    for (int c = 0; c < 8; ++c) {
        float4 v = *(const float4*)&row[c * 256 + lane * 4];
        float vv[4] = {v.x, v.y, v.z, v.w};
        #pragma unroll
        for (int r = 0; r < 4; ++r) {
            unsigned u = __float_as_uint(vv[r]);
            unsigned k = ((int)u >= 0) ? (u | 0x80000000u) : ~u;
            key[c * 4 + r] = k;
            kmin = kmin < k ? kmin : k;
            kmax = kmax > k ? kmax : k;
        }
    }
    kmin = wred_umin(kmin);
    kmax = wred_umax(kmax);

    // bisection: T = smallest m with #{key > m} < 20, T in [kmin, kmax]
    unsigned lo = kmin, hi = kmax;
    while (lo < hi) {
        unsigned mid = lo + ((hi - lo) >> 1);
        int cnt = 0;
        #pragma unroll
        for (int e = 0; e < 32; ++e) cnt += (key[e] > mid) ? 1 : 0;
        cnt = wred_add(cnt);                       // uniform (SGPR)
        if (cnt < KNN) hi = mid; else lo = mid + 1;
    }
    const unsigned T = lo;

    int* outp = idx_out + (size_t)qloc * KNN;
    const unsigned long long ltmask = (lane == 0) ? 0ull : (~0ull >> (64 - lane));
    int base = 0;
    #pragma unroll
    for (int e = 0; e < 32; ++e) {
        bool p = key[e] > T;
        unsigned long long m = __ballot(p);
        if (p) {
            int pos = base + __popcll(m & ltmask);
            outp[pos] = (e >> 2) * 256 + lane * 4 + (e & 3);
        }
        base += __popcll(m);
    }
    for (int e = 0; e < 32 && base < KNN; ++e) {
        bool p = key[e] == T;
        unsigned long long m = __ballot(p);
        if (p) {
            int pos = base + __popcll(m & ltmask);
            if (pos < KNN) outp[pos] = (e >> 2) * 256 + lane * 4 + (e & 3);
        }
        base += __popcll(m);
    }
}

// ---------------------------------------------------------------- gather + stats
template<int O, int NSEQ>
__launch_bounds__(256)
__global__ void k_gather(const float* __restrict__ gtab, const float* __restrict__ dtab,
                         const int* __restrict__ idx,
                         float* __restrict__ hmax, float* __restrict__ hmin,
                         float* __restrict__ ssum, float* __restrict__ ssumsq)
{
    constexpr int NPB = 256 / O;
    const int grp = threadIdx.x / O;
    const int o   = threadIdx.x & (O - 1);
    float accS = 0.f, accS2 = 0.f;
    const int rowsPerBlock = NPB * NSEQ;
    const int batch = blockIdx.x & 3;
    const int chunk = blockIdx.x >> 2;
    const int bbase = batch << 11;
    for (int s = 0; s < NSEQ; ++s) {
        int row = bbase + chunk * rowsPerBlock + s * NPB + grp;
        const int* ip = idx + (size_t)row * KNN;
        float gmax = -INFINITY, gmin = INFINITY, gs = 0.f, gs2 = 0.f;
        for (int k = 0; k < KNN; ++k) {
            int nb = ip[k];
            float v = gtab[(size_t)(bbase + nb) * O + o];
            gmax = fmaxf(gmax, v);
            gmin = fminf(gmin, v);
            gs  += v;
            gs2  = fmaf(v, v, gs2);
        }
        float d = dtab[(size_t)row * O + o];
        hmax[(size_t)row * O + o] = gmax + d;
        hmin[(size_t)row * O + o] = gmin + d;
        accS  += gs + (float)KNN * d;
        accS2 += gs2 + 2.f * d * gs + (float)KNN * d * d;
    }
    int bank = blockIdx.x & 63;
    atomicAdd(&ssum[bank * O + o], accS);
    atomicAdd(&ssumsq[bank * O + o], accS2);
}

// ---------------------------------------------------------------- normalize (+BN finalize, +xx, +bf16 mirror)
template<int O, bool WRITE_XX>
__launch_bounds__(256)
__global__ void k_normalize(const float* __restrict__ hmax, const float* __restrict__ hmin,
                            const float* __restrict__ ssum, const float* __restrict__ ssumsq,
                            const float* __restrict__ gamma, const float* __restrict__ beta,
                            float invM, float* __restrict__ xcs,
                            __hip_bfloat16* __restrict__ xch, float* __restrict__ xx)
{
    const int tid = threadIdx.x;
    const int o   = tid & (O - 1);
    float s = 0.f, s2 = 0.f;
    #pragma unroll 8
    for (int bk = 0; bk < 64; ++bk) { s += ssum[bk * O + o]; s2 += ssumsq[bk * O + o]; }
    float mean = s * invM;
    float var  = fmaf(-mean, mean, s2 * invM);
    float sc   = gamma[o] * rsqrtf(var + EPSV);
    float sh   = beta[o] - mean * sc;

    constexpr int R = 256 / O;
    const int rloc = tid / O;
    __shared__ float part[4];
    const int ngroups = BN_ROWS / R;
    for (int gidx = blockIdx.x; gidx < ngroups; gidx += gridDim.x) {
        int row = gidx * R + rloc;
        size_t i = (size_t)row * O + o;
        float h = (sc >= 0.f) ? hmax[i] : hmin[i];
        float y = fmaf(h, sc, sh);
        y = (y >= 0.f) ? y : SLOPEV * y;
        xcs[(size_t)row * 512 + o] = y;
        xch[(size_t)row * 512 + o] = __float2bfloat16(y);
        if constexpr (WRITE_XX) {
            float p = y * y;
            #pragma unroll
            for (int sft = 32; sft >= 1; sft >>= 1) p += __shfl_xor(p, sft, 64);
            if constexpr (O == 64) {
                if ((tid & 63) == 0) xx[row] = p;
            } else {
                if ((tid & 63) == 0) part[tid >> 6] = p;
                __syncthreads();
                if constexpr (O == 128) {
                    if (tid < 2) xx[gidx * R + tid] = part[2 * tid] + part[2 * tid + 1];
                } else {
                    if (tid == 0) xx[gidx * R] = (part[0] + part[1]) + (part[2] + part[3]);
                }
                __syncthreads();
            }
        }
    }
}

// ---------------------------------------------------------------- seg max/sum (+finalize, 64 banks)
__global__ void k_seg(const float* __restrict__ h,
                      const float* __restrict__ ssum, const float* __restrict__ ssumsq,
                      const float* __restrict__ gamma, const float* __restrict__ beta,
                      float* __restrict__ smax, float* __restrict__ ssumseg)
{
    int f = blockIdx.y * 256 + threadIdx.x;
    float s = 0.f, s2 = 0.f;
    #pragma unroll 8
    for (int bk = 0; bk < 64; ++bk) { s += ssum[bk * 1024 + f]; s2 += ssumsq[bk * 1024 + f]; }
    const float invM = 1.f / (float)BN_ROWS;
    float mean = s * invM;
    float var  = fmaf(-mean, mean, s2 * invM);
    float sc   = gamma[f] * rsqrtf(var + EPSV);
    float sh   = beta[f] - mean * sc;

    int seg = blockIdx.x;
    float mx = -INFINITY, sm = 0.f;
    int n0 = seg * 64;
    for (int i = 0; i < 64; ++i) {
        float v = fmaf(h[(size_t)(n0 + i) * 1024 + f], sc, sh);
        v = (v >= 0.f) ? v : SLOPEV * v;
        mx = fmaxf(mx, v); sm += v;
    }
    smax[(size_t)seg * 1024 + f]    = mx;
    ssumseg[(size_t)seg * 1024 + f] = sm;
}

// ---------------------------------------------------------------- final projection (+bin combine)
__launch_bounds__(256)
__global__ void k_final(const float* __restrict__ smax, const float* __restrict__ ssg,
                        const float* __restrict__ Wft, const float* __restrict__ bfeat,
                        float* __restrict__ out)
{
    __shared__ float row[1024];
    __shared__ float part[1024];
    const int tid = threadIdx.x;
    int sb = blockIdx.x;             // s*4 + b, s in 0..62
    int s = sb >> 2, b = sb & 3;
    int nb = (s == 0) ? 1 : (s < 3) ? 2 : (s < 7) ? 4 : (s < 15) ? 8 : (s < 31) ? 16 : 32;
    int idxL = s - (nb - 1);
    int segc = 32 / nb;
    int seg0 = b * 32 + idxL * segc;
    float inv = 1.f / (float)(64 * segc);
    for (int c = tid; c < 1024; c += 256) {
        float mx = -INFINITY, sm = 0.f;
        for (int t = 0; t < segc; ++t) {
            mx = fmaxf(mx, smax[(size_t)(seg0 + t) * 1024 + c]);
            sm += ssg[(size_t)(seg0 + t) * 1024 + c];
        }
        row[c] = mx + sm * inv;
    }
    __syncthreads();

    const int lane = tid & 63;
    const int w    = tid >> 6;
    const float* rw = row + w * 256;
    const float* wp = Wft + (size_t)(w * 256) * 256 + lane * 4;
    float4 a0 = {0,0,0,0}, a1 = {0,0,0,0}, a2 = {0,0,0,0}, a3 = {0,0,0,0};
    for (int f = 0; f < 256; f += 4) {
        float r0 = rw[f + 0], r1 = rw[f + 1], r2 = rw[f + 2], r3 = rw[f + 3];
        float4 w0 = *(const float4*)&wp[(size_t)(f + 0) * 256];
        float4 w1 = *(const float4*)&wp[(size_t)(f + 1) * 256];
        float4 w2 = *(const float4*)&wp[(size_t)(f + 2) * 256];
        float4 w3 = *(const float4*)&wp[(size_t)(f + 3) * 256];
        a0.x = fmaf(r0, w0.x, a0.x); a0.y = fmaf(r0, w0.y, a0.y);
        a0.z = fmaf(r0, w0.z, a0.z); a0.w = fmaf(r0, w0.w, a0.w);
        a1.x = fmaf(r1, w1.x, a1.x); a1.y = fmaf(r1, w1.y, a1.y);
        a1.z = fmaf(r1, w1.z, a1.z); a1.w = fmaf(r1, w1.w, a1.w);
        a2.x = fmaf(r2, w2.x, a2.x); a2.y = fmaf(r2, w2.y, a2.y);
        a2.z = fmaf(r2, w2.z, a2.z); a2.w = fmaf(r2, w2.w, a2.w);
        a3.x = fmaf(r3, w3.x, a3.x); a3.y = fmaf(r3, w3.y, a3.y);
        a3.z = fmaf(r3, w3.z, a3.z); a3.w = fmaf(r3, w3.w, a3.w);
    }
    float4 a;
    a.x = (a0.x + a1.x) + (a2.x + a3.x);
    a.y = (a0.y + a1.y) + (a2.y + a3.y);
    a.z = (a0.z + a1.z) + (a2.z + a3.z);
    a.w = (a0.w + a1.w) + (a2.w + a3.w);
    *(float4*)&part[w * 256 + lane * 4] = a;
    __syncthreads();
    int o = tid;
    float acc = (part[o] + part[256 + o]) + (part[512 + o] + part[768 + o]);
    out[(size_t)sb * 256 + o] = acc + bfeat[o];
}

// ================================================================ launch
extern "C" void kernel_launch(void* const* d_in, const int* in_sizes, int n_in,
                              void* d_out, int out_size, void* d_ws, size_t ws_size,
                              hipStream_t stream)
{
    const float* x  = (const float*)d_in[0];
    const float* W1 = (const float*)d_in[1];
    const float* g1 = (const float*)d_in[2];
    const float* b1 = (const float*)d_in[3];
    const float* W2 = (const float*)d_in[4];
    const float* g2 = (const float*)d_in[5];
    const float* b2 = (const float*)d_in[6];
    const float* W3 = (const float*)d_in[7];
    const float* g3 = (const float*)d_in[8];
    const float* b3 = (const float*)d_in[9];
    const float* W4 = (const float*)d_in[10];
    const float* g4 = (const float*)d_in[11];
    const float* b4 = (const float*)d_in[12];
    const float* W5 = (const float*)d_in[13];
    const float* g5 = (const float*)d_in[14];
    const float* b5 = (const float*)d_in[15];
    const float* Wf = (const float*)d_in[16];
    const float* bfeat = (const float*)d_in[17];
    float* out = (float*)d_out;
    float* ws  = (float*)d_ws;

    // workspace layout (floats), total 28,533,248 = 114.1 MB (ws_size ~268 MB)
    float* xt1   = ws + 0;            // 24576
    int*   idx   = (int*)(ws + 24576);// 163840
    float* xx    = ws + 188416;       // 8192
    float* xc    = ws + 196608;       // 8192*512
    float* hmax  = ws + 4390912;      // 8192*256
    float* hmin  = ws + 6488064;      // 8192*256
    float* stats = ws + 8585216;      // 65536 (L1@0 L2@8192 L3@16384 L4@32768)
    float* smax  = ws + 8650752;      // 128*1024
    float* ssg   = ws + 8781824;      // 128*1024
    float* wc    = ws + 8912896;      // 90624
    float* big   = ws + 9003520;      // 16,777,216 (4-batch D2 | gtab+dtab | h5)
    float* gtab  = big;               // up to 8192*256
    float* dtab  = big + 2097152;     // up to 8192*256
    __hip_bfloat16* xch = (__hip_bfloat16*)(ws + 25780736);  // 8192*512 bf16
    __hip_bfloat16* w5h = (__hip_bfloat16*)(ws + 27877888);  // 1024*512 bf16
    float* wft   = ws + 28140032;     // 1024*256 transposed Wf
    float* l5s   = ws + 28402176;     // 64*1024 L5 col sums
    float* l5q   = ws + 28467712;     // 64*1024 L5 col sumsq

    hipMemsetAsync(stats, 0, 65536 * sizeof(float), stream);
    k_transpose<<<32, 256, 0, stream>>>(x, xt1, xx);
    k_prepw_all<<<3426, 256, 0, stream>>>(W1, W2, W3, W4, W5, Wf, wc, w5h, wft);

    const float invMk = 1.f / (float)(BN_ROWS * KNN);

    // ------------- layer 1: C=3, O=64
    {
        float* ss = stats + 0;
        k_mm128<MODE_DIST, false><<<dim3(136, 1, 4), 256, 0, stream>>>(xt1, 3, nullptr, 0, xx, 0, big, nullptr, N_PTS, 3);
        k_select<<<2048, 256, 0, stream>>>(big, idx);
        k_mm128<MODE_GD, false><<<dim3(2, 64, 1), 256, 0, stream>>>(xt1, 3, wc, 3, nullptr, 0, gtab, dtab, 128, 3);
        k_gather<64, 8><<<256, 256, 0, stream>>>(gtab, dtab, idx, hmax, hmin, ss, ss + 4096);
        k_normalize<64, true><<<512, 256, 0, stream>>>(hmax, hmin, ss, ss + 4096, g1, b1, invMk, xc + 0, xch + 0, xx);
    }
    // ------------- layer 2: C=64, O=64
    {
        float* ss = stats + 8192;
        k_mm128<MODE_DIST, true><<<dim3(136, 1, 4), 256, 0, stream>>>(xc + 0, 512, nullptr, 0, xx, 0, big, nullptr, N_PTS, 64);
        k_select<<<2048, 256, 0, stream>>>(big, idx);
        k_mm128<MODE_GD, true><<<dim3(2, 64, 1), 256, 0, stream>>>(xc + 0, 512, wc + 384, 64, nullptr, 0, gtab, dtab, 128, 64);
        k_gather<64, 8><<<256, 256, 0, stream>>>(gtab, dtab, idx, hmax, hmin, ss, ss + 4096);
        k_normalize<64, true><<<512, 256, 0, stream>>>(hmax, hmin, ss, ss + 4096, g2, b2, invMk, xc + 64, xch + 64, xx);
    }
    // ------------- layer 3: C=64, O=128
    {
        float* ss = stats + 16384;
        k_mm128<MODE_DIST, true><<<dim3(136, 1, 4), 256, 0, stream>>>(xc + 64, 512, nullptr, 0, xx, 0, big, nullptr, N_PTS, 64);
        k_select<<<2048, 256, 0, stream>>>(big, idx);
        k_mm128<MODE_GD, true><<<dim3(4, 64, 1), 256, 0, stream>>>(xc + 64, 512, wc + 8576, 64, nullptr, 0, gtab, dtab, 256, 64);
        k_gather<128, 8><<<512, 256, 0, stream>>>(gtab, dtab, idx, hmax, hmin, ss, ss + 8192);
        k_normalize<128, true><<<512, 256, 0, stream>>>(hmax, hmin, ss, ss + 8192, g3, b3, invMk, xc + 128, xch + 128, xx);
    }
    // ------------- layer 4: C=128, O=256
    {
        float* ss = stats + 32768;
        k_mm128<MODE_DIST, true><<<dim3(136, 1, 4), 256, 0, stream>>>(xc + 128, 512, nullptr, 0, xx, 0, big, nullptr, N_PTS, 128);
        k_select<<<2048, 256, 0, stream>>>(big, idx);
        k_mm128<MODE_GD, true><<<dim3(8, 64, 1), 256, 0, stream>>>(xc + 128, 512, wc + 24960, 128, nullptr, 0, gtab, dtab, 512, 128);
        k_gather<256, 8><<<1024, 256, 0, stream>>>(gtab, dtab, idx, hmax, hmin, ss, ss + 16384);
        k_normalize<256, false><<<512, 256, 0, stream>>>(hmax, hmin, ss, ss + 16384, g4, b4, invMk, xc + 256, xch + 256, xx);
    }
    // ------------- layer 5: bf16 MFMA GEMM (+fused stats), seg, final
    {
        k_gemm5<<<dim3(8, 64), 256, 0, stream>>>((const unsigned short*)xch, (const unsigned short*)w5h, big, l5s, l5q);
        k_seg<<<dim3(128, 4), 256, 0, stream>>>(big, l5s, l5q, g5, b5, smax, ssg);
        k_final<<<252, 256, 0, stream>>>(smax, ssg, wft, bfeat, out);
    }
}

// Round 15
// 600.442 us; speedup vs baseline: 1.1106x; 1.1106x over previous
//
#include <hip/hip_runtime.h>
#include <hip/hip_bf16.h>
#include <cstdint>
#include <cstddef>

#define B_SZ   4
#define N_PTS  2048
#define KNN    20
#define BN_ROWS (B_SZ * N_PTS)
#define EPSV   1e-5f
#define SLOPEV 0.2f

#define MODE_GD   0
#define MODE_DIST 1

typedef __attribute__((ext_vector_type(8))) short bf16x8;
typedef __attribute__((ext_vector_type(4))) float f32x4;

// ---------------------------------------------------------------- transpose + xx
__global__ void k_transpose(const float* __restrict__ x, float* __restrict__ xt,
                            float* __restrict__ xx)
{
    int i = blockIdx.x * 256 + threadIdx.x;
    if (i >= BN_ROWS) return;
    int b = i >> 11, n = i & 2047;
    float v0 = x[((b * 3 + 0) << 11) + n];
    float v1 = x[((b * 3 + 1) << 11) + n];
    float v2 = x[((b * 3 + 2) << 11) + n];
    xt[i * 3 + 0] = v0; xt[i * 3 + 1] = v1; xt[i * 3 + 2] = v2;
    xx[i] = fmaf(v0, v0, fmaf(v1, v1, v2 * v2));
}

// ---------------------------------------------------------------- batched weight prep
__global__ void k_prepw_all(const float* __restrict__ W1, const float* __restrict__ W2,
                            const float* __restrict__ W3, const float* __restrict__ W4,
                            const float* __restrict__ W5, const float* __restrict__ Wf,
                            float* __restrict__ wc, __hip_bfloat16* __restrict__ w5h,
                            float* __restrict__ wft)
{
    int i = blockIdx.x * 256 + threadIdx.x;
    if (i >= 876928) return;
    if (i >= 614784) {                      // Wf transpose
        int e = i - 614784;                 // e = o*1024 + f
        int o = e >> 10, f = e & 1023;
        wft[f * 256 + o] = Wf[e];
        return;
    }
    if (i >= 90496) {                       // W5 (1024x512) -> bf16
        int e = i - 90496;
        w5h[e] = __float2bfloat16(W5[e]);
        return;
    }
    const float* W; int O, C, off;
    if      (i < 384)   { W = W1; O = 64;  C = 3;   off = 0; }
    else if (i < 8576)  { W = W2; O = 64;  C = 64;  off = 384; }
    else if (i < 24960) { W = W3; O = 128; C = 64;  off = 8576; }
    else                { W = W4; O = 256; C = 128; off = 24960; }
    int e = i - off, j = e / C, c = e - j * C;
    float v;
    if (j < O) v = W[j * 2 * C + c];
    else { int jo = j - O; v = W[jo * 2 * C + C + c] - W[jo * 2 * C + c]; }
    wc[i] = v;
}

// ---------------------------------------------------------------- GEMM core
// MODE_GD  : 128x64 tile. C = A(MxK) @ Bm(NnxK)^T, grid (Nn/64, M/128).
// MODE_DIST: 128x128 SYMMETRIC tile, grid (136, 1, 4). 120 off-diagonal pairs
//   first, 16 diagonal tiles last (cheap tail — no mirror epilogue). Diagonal
//   forced to exact 0; D2 bitwise identical to previous rounds.
template<int MODE, bool VEC>
__launch_bounds__(256)
__global__ void k_mm128(const float* __restrict__ A, int lda,
                        const float* __restrict__ Bm, int ldb,
                        const float* __restrict__ xx, int b0,
                        float* __restrict__ C1, float* __restrict__ C2,
                        int Nn, int Kd)
{
    constexpr int LDA_ = 132;     // 128 + 4 pad
    constexpr int LDB_ = (MODE == MODE_DIST) ? 132 : 68;
    constexpr int SMEMF = 32 * LDA_ + 32 * LDB_;   // DIST: 8448, GD: 6400
    __shared__ float smem[SMEMF];
    float* As = smem;
    float* Bs = smem + 32 * LDA_;
    float* T  = smem;             // DIST mirror transpose: 64 x 132 = 8448 == SMEMF
    const int tid = threadIdx.x;
    const int tx  = tid & 15;
    const int ty  = tid >> 4;

    int m0, n0;
    if constexpr (MODE == MODE_DIST) {
        int t = blockIdx.x;
        int it, jt;
        if (t < 120) {                     // off-diagonal pairs first
            int i = 0;
            for (; i < 15; ++i) { int cnt = 15 - i; if (t < cnt) break; t -= cnt; }
            it = i; jt = i + 1 + t;
        } else {                           // 16 diagonal tiles last (no mirror)
            it = jt = t - 120;
        }
        m0 = it * 128;
        n0 = jt * 128;
    } else {
        m0 = blockIdx.y * 128;
        n0 = blockIdx.x * 64;
    }

    const float* Ab;
    const float* Bb;
    int ldbe;
    if constexpr (MODE == MODE_DIST) {
        const int b = b0 + blockIdx.z;
        Ab = A + (size_t)b * N_PTS * lda;
        Bb = Ab;
        ldbe = lda;
    } else {
        Ab = A; Bb = Bm; ldbe = ldb;
    }

    constexpr int NJH = (MODE == MODE_DIST) ? 2 : 1;
    float acc[2][NJH][4][4] = {};

    for (int k0 = 0; k0 < Kd; k0 += 32) {
        #pragma unroll
        for (int r = 0; r < 4; ++r) {            // A: 128 rows x 32 k
            int e = r * 256 + tid, row = e >> 3, kq = e & 7;
            if constexpr (VEC) {
                float4 v = *(const float4*)&Ab[(size_t)(m0 + row) * lda + k0 + kq * 4];
                As[(kq * 4 + 0) * LDA_ + row] = v.x;
                As[(kq * 4 + 1) * LDA_ + row] = v.y;
                As[(kq * 4 + 2) * LDA_ + row] = v.z;
                As[(kq * 4 + 3) * LDA_ + row] = v.w;
            } else {
                #pragma unroll
                for (int j = 0; j < 4; ++j) {
                    int kg = k0 + kq * 4 + j;
                    As[(kq * 4 + j) * LDA_ + row] =
                        (kg < Kd) ? Ab[(size_t)(m0 + row) * lda + kg] : 0.f;
                }
            }
        }
        constexpr int BR = (MODE == MODE_DIST) ? 4 : 2;
        #pragma unroll
        for (int r = 0; r < BR; ++r) {
            int e = r * 256 + tid, row = e >> 3, kq = e & 7;
            if constexpr (VEC) {
                float4 v = *(const float4*)&Bb[(size_t)(n0 + row) * ldbe + k0 + kq * 4];
                Bs[(kq * 4 + 0) * LDB_ + row] = v.x;
                Bs[(kq * 4 + 1) * LDB_ + row] = v.y;
                Bs[(kq * 4 + 2) * LDB_ + row] = v.z;
                Bs[(kq * 4 + 3) * LDB_ + row] = v.w;
            } else {
                #pragma unroll
                for (int j = 0; j < 4; ++j) {
                    int kg = k0 + kq * 4 + j;
                    Bs[(kq * 4 + j) * LDB_ + row] =
                        (kg < Kd) ? Bb[(size_t)(n0 + row) * ldbe + kg] : 0.f;
                }
            }
        }
        __syncthreads();

        int klen = Kd - k0; if (klen > 32) klen = 32;
        #pragma unroll 8
        for (int kk = 0; kk < klen; ++kk) {
            float4 a0 = *(const float4*)&As[kk * LDA_ + ty * 4];
            float4 a1 = *(const float4*)&As[kk * LDA_ + 64 + ty * 4];
            float av[2][4] = {{a0.x,a0.y,a0.z,a0.w},{a1.x,a1.y,a1.z,a1.w}};
            if constexpr (MODE == MODE_DIST) {
                float4 b0q = *(const float4*)&Bs[kk * LDB_ + tx * 4];
                float4 b1q = *(const float4*)&Bs[kk * LDB_ + 64 + tx * 4];
                float bw[2][4] = {{b0q.x,b0q.y,b0q.z,b0q.w},{b1q.x,b1q.y,b1q.z,b1q.w}};
                #pragma unroll
                for (int ih = 0; ih < 2; ++ih)
                    #pragma unroll
                    for (int jh = 0; jh < 2; ++jh)
                        #pragma unroll
                        for (int ii = 0; ii < 4; ++ii)
                            #pragma unroll
                            for (int jj = 0; jj < 4; ++jj)
                                acc[ih][jh][ii][jj] = fmaf(av[ih][ii], bw[jh][jj], acc[ih][jh][ii][jj]);
            } else {
                float4 bq = *(const float4*)&Bs[kk * LDB_ + tx * 4];
                float bw[4] = {bq.x, bq.y, bq.z, bq.w};
                #pragma unroll
                for (int ih = 0; ih < 2; ++ih)
                    #pragma unroll
                    for (int ii = 0; ii < 4; ++ii)
                        #pragma unroll
                        for (int jj = 0; jj < 4; ++jj)
                            acc[ih][0][ii][jj] = fmaf(av[ih][ii], bw[jj], acc[ih][0][ii][jj]);
            }
        }
        __syncthreads();
    }

    if constexpr (MODE == MODE_DIST) {
        const float* xxb = xx + (b0 + blockIdx.z) * N_PTS;
        float xj[2][4];
        #pragma unroll
        for (int jh = 0; jh < 2; ++jh) {
            float4 v = *(const float4*)&xxb[n0 + jh * 64 + tx * 4];
            xj[jh][0] = v.x; xj[jh][1] = v.y; xj[jh][2] = v.z; xj[jh][3] = v.w;
        }
        float xiv[2][4];
        #pragma unroll
        for (int ih = 0; ih < 2; ++ih)
            #pragma unroll
            for (int i = 0; i < 4; ++i)
                xiv[ih][i] = xxb[m0 + ih * 64 + ty * 4 + i];
        const bool diag = (m0 == n0);
        const size_t zoff = (size_t)blockIdx.z * N_PTS;

        #pragma unroll
        for (int ih = 0; ih < 2; ++ih)
            #pragma unroll
            for (int i = 0; i < 4; ++i) {
                int gi = m0 + ih * 64 + ty * 4 + i;
                float xi = xiv[ih][i];
                size_t base = (zoff + gi) * N_PTS;
                #pragma unroll
                for (int jh = 0; jh < 2; ++jh) {
                    int gj = n0 + jh * 64 + tx * 4;
                    float4 v;
                    v.x = 2.f * acc[ih][jh][i][0] - xi - xj[jh][0];
                    v.y = 2.f * acc[ih][jh][i][1] - xi - xj[jh][1];
                    v.z = 2.f * acc[ih][jh][i][2] - xi - xj[jh][2];
                    v.w = 2.f * acc[ih][jh][i][3] - xi - xj[jh][3];
                    if (diag) {
                        if (gi == gj + 0) v.x = 0.f;
                        if (gi == gj + 1) v.y = 0.f;
                        if (gi == gj + 2) v.z = 0.f;
                        if (gi == gj + 3) v.w = 0.f;
                    }
                    *(float4*)&C1[base + gj] = v;
                }
            }

        if (!diag) {
            #pragma unroll
            for (int jh = 0; jh < 2; ++jh) {
                #pragma unroll
                for (int c = 0; c < 4; ++c) {
                    float xjc = xj[jh][c];
                    #pragma unroll
                    for (int ih = 0; ih < 2; ++ih) {
                        float4 tv;
                        tv.x = 2.f * acc[ih][jh][0][c] - xjc - xiv[ih][0];
                        tv.y = 2.f * acc[ih][jh][1][c] - xjc - xiv[ih][1];
                        tv.z = 2.f * acc[ih][jh][2][c] - xjc - xiv[ih][2];
                        tv.w = 2.f * acc[ih][jh][3][c] - xjc - xiv[ih][3];
                        *(float4*)&T[(tx * 4 + c) * LDA_ + ih * 64 + ty * 4] = tv;
                    }
                }
                __syncthreads();
                #pragma unroll
                for (int r = 0; r < 8; ++r) {
                    int e = r * 256 + tid;
                    int jr = e >> 5, c4 = e & 31;
                    float4 tv = *(const float4*)&T[jr * LDA_ + c4 * 4];
                    *(float4*)&C1[(zoff + n0 + jh * 64 + jr) * N_PTS + m0 + c4 * 4] = tv;
                }
                __syncthreads();
            }
        }
    } else {  // MODE_GD
        const int Oo = Nn >> 1;
        #pragma unroll
        for (int ih = 0; ih < 2; ++ih)
            #pragma unroll
            for (int i = 0; i < 4; ++i) {
                int row = m0 + ih * 64 + ty * 4 + i;
                int colg = n0 + tx * 4;
                float4 v = make_float4(acc[ih][0][i][0], acc[ih][0][i][1],
                                       acc[ih][0][i][2], acc[ih][0][i][3]);
                if (colg < Oo) *(float4*)&C1[(size_t)row * Oo + colg] = v;
                else           *(float4*)&C2[(size_t)row * Oo + colg - Oo] = v;
            }
    }
}

// ---------------------------------------------------------------- bf16 MFMA GEMM (layer 5)
__launch_bounds__(256)
__global__ void k_gemm5(const unsigned short* __restrict__ Ah,
                        const unsigned short* __restrict__ Bh,
                        float* __restrict__ Cf,
                        float* __restrict__ ssum, float* __restrict__ ssumsq)
{
    constexpr int LDA = 72;
    __shared__ unsigned short As[128 * LDA];
    __shared__ unsigned short Bs[128 * LDA];
    const int tid  = threadIdx.x;
    const int lane = tid & 63;
    const int w    = tid >> 6;
    const int wr   = w >> 1, wcl = w & 1;
    const int quad = lane >> 4;
    const int l16  = lane & 15;
    const int m0 = blockIdx.y * 128;
    const int n0 = blockIdx.x * 128;

    f32x4 acc[4][4] = {};

    for (int k0 = 0; k0 < 512; k0 += 64) {
        #pragma unroll
        for (int r = 0; r < 4; ++r) {
            int e = r * 256 + tid, row = e >> 3, kq = e & 7;
            *(uint4*)&As[row * LDA + kq * 8] =
                *(const uint4*)&Ah[(size_t)(m0 + row) * 512 + k0 + kq * 8];
        }
        #pragma unroll
        for (int r = 0; r < 4; ++r) {
            int e = r * 256 + tid, row = e >> 3, kq = e & 7;
            *(uint4*)&Bs[row * LDA + kq * 8] =
                *(const uint4*)&Bh[(size_t)(n0 + row) * 512 + k0 + kq * 8];
        }
        __syncthreads();
        #pragma unroll
        for (int kk = 0; kk < 64; kk += 32) {
            bf16x8 af[4], bfr[4];
            #pragma unroll
            for (int i = 0; i < 4; ++i)
                af[i] = *(const bf16x8*)&As[(wr * 64 + i * 16 + l16) * LDA + kk + quad * 8];
            #pragma unroll
            for (int j = 0; j < 4; ++j)
                bfr[j] = *(const bf16x8*)&Bs[(wcl * 64 + j * 16 + l16) * LDA + kk + quad * 8];
            #pragma unroll
            for (int i = 0; i < 4; ++i)
                #pragma unroll
                for (int j = 0; j < 4; ++j)
                    acc[i][j] = __builtin_amdgcn_mfma_f32_16x16x32_bf16(af[i], bfr[j], acc[i][j], 0, 0, 0);
        }
        __syncthreads();
    }

    #pragma unroll
    for (int i = 0; i < 4; ++i) {
        int rbase = m0 + wr * 64 + i * 16 + quad * 4;
        #pragma unroll
        for (int j = 0; j < 4; ++j) {
            int col = n0 + wcl * 64 + j * 16 + l16;
            #pragma unroll
            for (int r = 0; r < 4; ++r)
                Cf[(size_t)(rbase + r) * 1024 + col] = acc[i][j][r];
        }
    }

    float* sredS = (float*)As;
    float* sredQ = (float*)Bs;
    #pragma unroll
    for (int j = 0; j < 4; ++j) {
        float s = 0.f, q = 0.f;
        #pragma unroll
        for (int i = 0; i < 4; ++i)
            #pragma unroll
            for (int r = 0; r < 4; ++r) {
                float v = acc[i][j][r];
                s += v; q = fmaf(v, v, q);
            }
        int coll = wcl * 64 + j * 16 + l16;
        int slot = wr * 4 + quad;
        sredS[coll * 8 + slot] = s;
        sredQ[coll * 8 + slot] = q;
    }
    __syncthreads();
    if (tid < 128) {
        float s = 0.f, q = 0.f;
        #pragma unroll
        for (int t = 0; t < 8; ++t) { s += sredS[tid * 8 + t]; q += sredQ[tid * 8 + t]; }
        ssum  [blockIdx.y * 1024 + n0 + tid] = s;
        ssumsq[blockIdx.y * 1024 + n0 + tid] = q;
    }
}

// ---------------------------------------------------------------- top-20 select (all 4 batches)
// Bisection counting via __ballot + popcount: v_cmp (VALU) + s_bcnt1/s_add
// (SALU, co-issued free). No cross-lane reduce at all — ballot IS the
// reduction, and the count is wave-uniform (scalar branch). Round-14's DPP
// chains regressed (85% VALUBusy); round-13's bpermute butterfly was ~70
// VALU/iter; this is ~32 VALU/iter.
__launch_bounds__(256)
__global__ void k_select(const float* __restrict__ D2, int* __restrict__ idx_out)
{
    const int lane = threadIdx.x & 63;
    const int w    = threadIdx.x >> 6;
    const int qloc = blockIdx.x * 4 + w;          // 0..8191
    const float* row = D2 + (size_t)qloc * N_PTS;

    unsigned key[32];
    #pragma unroll
    for (int c = 0; c < 8; ++c) {
        float4 v = *(const float4*)&row[c * 256 + lane * 4];
        float vv[4] = {v.x, v.y, v.z, v.w};
        #pragma unroll
        for (int r = 0; r < 4; ++r) {
            unsigned u = __float_as_uint(vv[r]);
            key[c * 4 + r] = ((int)u >= 0) ? (u | 0x80000000u) : ~u;
        }
    }

    // bisection: T = smallest m with #{key > m} < 20
    unsigned lo = 0u, hi = 0xFFFFFFFFu;
    while (lo < hi) {
        unsigned mid = lo + ((hi - lo) >> 1);
        int cnt = 0;
        #pragma unroll
        for (int e = 0; e < 32; ++e)
            cnt += __popcll(__ballot(key[e] > mid));
        if (cnt < KNN) hi = mid; else lo = mid + 1;
    }
    const unsigned T = lo;

    int* outp = idx_out + (size_t)qloc * KNN;
    const unsigned long long ltmask = (lane == 0) ? 0ull : (~0ull >> (64 - lane));
    int base = 0;
    #pragma unroll
    for (int e = 0; e < 32; ++e) {
        bool p = key[e] > T;
        unsigned long long m = __ballot(p);
        if (p) {
            int pos = base + __popcll(m & ltmask);
            outp[pos] = (e >> 2) * 256 + lane * 4 + (e & 3);
        }
        base += __popcll(m);
    }
    for (int e = 0; e < 32 && base < KNN; ++e) {
        bool p = key[e] == T;
        unsigned long long m = __ballot(p);
        if (p) {
            int pos = base + __popcll(m & ltmask);
            if (pos < KNN) outp[pos] = (e >> 2) * 256 + lane * 4 + (e & 3);
        }
        base += __popcll(m);
    }
}

// ---------------------------------------------------------------- gather + stats
template<int O, int NSEQ>
__launch_bounds__(256)
__global__ void k_gather(const float* __restrict__ gtab, const float* __restrict__ dtab,
                         const int* __restrict__ idx,
                         float* __restrict__ hmax, float* __restrict__ hmin,
                         float* __restrict__ ssum, float* __restrict__ ssumsq)
{
    constexpr int NPB = 256 / O;
    const int grp = threadIdx.x / O;
    const int o   = threadIdx.x & (O - 1);
    float accS = 0.f, accS2 = 0.f;
    const int rowsPerBlock = NPB * NSEQ;
    const int batch = blockIdx.x & 3;
    const int chunk = blockIdx.x >> 2;
    const int bbase = batch << 11;
    for (int s = 0; s < NSEQ; ++s) {
        int row = bbase + chunk * rowsPerBlock + s * NPB + grp;
        const int* ip = idx + (size_t)row * KNN;
        float gmax = -INFINITY, gmin = INFINITY, gs = 0.f, gs2 = 0.f;
        for (int k = 0; k < KNN; ++k) {
            int nb = ip[k];
            float v = gtab[(size_t)(bbase + nb) * O + o];
            gmax = fmaxf(gmax, v);
            gmin = fminf(gmin, v);
            gs  += v;
            gs2  = fmaf(v, v, gs2);
        }
        float d = dtab[(size_t)row * O + o];
        hmax[(size_t)row * O + o] = gmax + d;
        hmin[(size_t)row * O + o] = gmin + d;
        accS  += gs + (float)KNN * d;
        accS2 += gs2 + 2.f * d * gs + (float)KNN * d * d;
    }
    int bank = blockIdx.x & 63;
    atomicAdd(&ssum[bank * O + o], accS);
    atomicAdd(&ssumsq[bank * O + o], accS2);
}

// ---------------------------------------------------------------- normalize (+BN finalize, +xx, +bf16 mirror)
template<int O, bool WRITE_XX>
__launch_bounds__(256)
__global__ void k_normalize(const float* __restrict__ hmax, const float* __restrict__ hmin,
                            const float* __restrict__ ssum, const float* __restrict__ ssumsq,
                            const float* __restrict__ gamma, const float* __restrict__ beta,
                            float invM, float* __restrict__ xcs,
                            __hip_bfloat16* __restrict__ xch, float* __restrict__ xx)
{
    const int tid = threadIdx.x;
    const int o   = tid & (O - 1);
    float s = 0.f, s2 = 0.f;
    #pragma unroll 8
    for (int bk = 0; bk < 64; ++bk) { s += ssum[bk * O + o]; s2 += ssumsq[bk * O + o]; }
    float mean = s * invM;
    float var  = fmaf(-mean, mean, s2 * invM);
    float sc   = gamma[o] * rsqrtf(var + EPSV);
    float sh   = beta[o] - mean * sc;

    constexpr int R = 256 / O;
    const int rloc = tid / O;
    __shared__ float part[4];
    const int ngroups = BN_ROWS / R;
    for (int gidx = blockIdx.x; gidx < ngroups; gidx += gridDim.x) {
        int row = gidx * R + rloc;
        size_t i = (size_t)row * O + o;
        float h = (sc >= 0.f) ? hmax[i] : hmin[i];
        float y = fmaf(h, sc, sh);
        y = (y >= 0.f) ? y : SLOPEV * y;
        xcs[(size_t)row * 512 + o] = y;
        xch[(size_t)row * 512 + o] = __float2bfloat16(y);
        if constexpr (WRITE_XX) {
            float p = y * y;
            #pragma unroll
            for (int sft = 32; sft >= 1; sft >>= 1) p += __shfl_xor(p, sft, 64);
            if constexpr (O == 64) {
                if ((tid & 63) == 0) xx[row] = p;
            } else {
                if ((tid & 63) == 0) part[tid >> 6] = p;
                __syncthreads();
                if constexpr (O == 128) {
                    if (tid < 2) xx[gidx * R + tid] = part[2 * tid] + part[2 * tid + 1];
                } else {
                    if (tid == 0) xx[gidx * R] = (part[0] + part[1]) + (part[2] + part[3]);
                }
                __syncthreads();
            }
        }
    }
}

// ---------------------------------------------------------------- seg max/sum (+finalize, 64 banks)
__global__ void k_seg(const float* __restrict__ h,
                      const float* __restrict__ ssum, const float* __restrict__ ssumsq,
                      const float* __restrict__ gamma, const float* __restrict__ beta,
                      float* __restrict__ smax, float* __restrict__ ssumseg)
{
    int f = blockIdx.y * 256 + threadIdx.x;
    float s = 0.f, s2 = 0.f;
    #pragma unroll 8
    for (int bk = 0; bk < 64; ++bk) { s += ssum[bk * 1024 + f]; s2 += ssumsq[bk * 1024 + f]; }
    const float invM = 1.f / (float)BN_ROWS;
    float mean = s * invM;
    float var  = fmaf(-mean, mean, s2 * invM);
    float sc   = gamma[f] * rsqrtf(var + EPSV);
    float sh   = beta[f] - mean * sc;

    int seg = blockIdx.x;
    float mx = -INFINITY, sm = 0.f;
    int n0 = seg * 64;
    for (int i = 0; i < 64; ++i) {
        float v = fmaf(h[(size_t)(n0 + i) * 1024 + f], sc, sh);
        v = (v >= 0.f) ? v : SLOPEV * v;
        mx = fmaxf(mx, v); sm += v;
    }
    smax[(size_t)seg * 1024 + f]    = mx;
    ssumseg[(size_t)seg * 1024 + f] = sm;
}

// ---------------------------------------------------------------- final projection (+bin combine)
__launch_bounds__(256)
__global__ void k_final(const float* __restrict__ smax, const float* __restrict__ ssg,
                        const float* __restrict__ Wft, const float* __restrict__ bfeat,
                        float* __restrict__ out)
{
    __shared__ float row[1024];
    __shared__ float part[1024];
    const int tid = threadIdx.x;
    int sb = blockIdx.x;             // s*4 + b, s in 0..62
    int s = sb >> 2, b = sb & 3;
    int nb = (s == 0) ? 1 : (s < 3) ? 2 : (s < 7) ? 4 : (s < 15) ? 8 : (s < 31) ? 16 : 32;
    int idxL = s - (nb - 1);
    int segc = 32 / nb;
    int seg0 = b * 32 + idxL * segc;
    float inv = 1.f / (float)(64 * segc);
    for (int c = tid; c < 1024; c += 256) {
        float mx = -INFINITY, sm = 0.f;
        for (int t = 0; t < segc; ++t) {
            mx = fmaxf(mx, smax[(size_t)(seg0 + t) * 1024 + c]);
            sm += ssg[(size_t)(seg0 + t) * 1024 + c];
        }
        row[c] = mx + sm * inv;
    }
    __syncthreads();

    const int lane = tid & 63;
    const int w    = tid >> 6;
    const float* rw = row + w * 256;
    const float* wp = Wft + (size_t)(w * 256) * 256 + lane * 4;
    float4 a0 = {0,0,0,0}, a1 = {0,0,0,0}, a2 = {0,0,0,0}, a3 = {0,0,0,0};
    for (int f = 0; f < 256; f += 4) {
        float r0 = rw[f + 0], r1 = rw[f + 1], r2 = rw[f + 2], r3 = rw[f + 3];
        float4 w0 = *(const float4*)&wp[(size_t)(f + 0) * 256];
        float4 w1 = *(const float4*)&wp[(size_t)(f + 1) * 256];
        float4 w2 = *(const float4*)&wp[(size_t)(f + 2) * 256];
        float4 w3 = *(const float4*)&wp[(size_t)(f + 3) * 256];
        a0.x = fmaf(r0, w0.x, a0.x); a0.y = fmaf(r0, w0.y, a0.y);
        a0.z = fmaf(r0, w0.z, a0.z); a0.w = fmaf(r0, w0.w, a0.w);
        a1.x = fmaf(r1, w1.x, a1.x); a1.y = fmaf(r1, w1.y, a1.y);
        a1.z = fmaf(r1, w1.z, a1.z); a1.w = fmaf(r1, w1.w, a1.w);
        a2.x = fmaf(r2, w2.x, a2.x); a2.y = fmaf(r2, w2.y, a2.y);
        a2.z = fmaf(r2, w2.z, a2.z); a2.w = fmaf(r2, w2.w, a2.w);
        a3.x = fmaf(r3, w3.x, a3.x); a3.y = fmaf(r3, w3.y, a3.y);
        a3.z = fmaf(r3, w3.z, a3.z); a3.w = fmaf(r3, w3.w, a3.w);
    }
    float4 a;
    a.x = (a0.x + a1.x) + (a2.x + a3.x);
    a.y = (a0.y + a1.y) + (a2.y + a3.y);
    a.z = (a0.z + a1.z) + (a2.z + a3.z);
    a.w = (a0.w + a1.w) + (a2.w + a3.w);
    *(float4*)&part[w * 256 + lane * 4] = a;
    __syncthreads();
    int o = tid;
    float acc = (part[o] + part[256 + o]) + (part[512 + o] + part[768 + o]);
    out[(size_t)sb * 256 + o] = acc + bfeat[o];
}

// ================================================================ launch
extern "C" void kernel_launch(void* const* d_in, const int* in_sizes, int n_in,
                              void* d_out, int out_size, void* d_ws, size_t ws_size,
                              hipStream_t stream)
{
    const float* x  = (const float*)d_in[0];
    const float* W1 = (const float*)d_in[1];
    const float* g1 = (const float*)d_in[2];
    const float* b1 = (const float*)d_in[3];
    const float* W2 = (const float*)d_in[4];
    const float* g2 = (const float*)d_in[5];
    const float* b2 = (const float*)d_in[6];
    const float* W3 = (const float*)d_in[7];
    const float* g3 = (const float*)d_in[8];
    const float* b3 = (const float*)d_in[9];
    const float* W4 = (const float*)d_in[10];
    const float* g4 = (const float*)d_in[11];
    const float* b4 = (const float*)d_in[12];
    const float* W5 = (const float*)d_in[13];
    const float* g5 = (const float*)d_in[14];
    const float* b5 = (const float*)d_in[15];
    const float* Wf = (const float*)d_in[16];
    const float* bfeat = (const float*)d_in[17];
    float* out = (float*)d_out;
    float* ws  = (float*)d_ws;

    // workspace layout (floats), total 28,533,248 = 114.1 MB (ws_size ~268 MB)
    float* xt1   = ws + 0;            // 24576
    int*   idx   = (int*)(ws + 24576);// 163840
    float* xx    = ws + 188416;       // 8192
    float* xc    = ws + 196608;       // 8192*512
    float* hmax  = ws + 4390912;      // 8192*256
    float* hmin  = ws + 6488064;      // 8192*256
    float* stats = ws + 8585216;      // 65536 (L1@0 L2@8192 L3@16384 L4@32768)
    float* smax  = ws + 8650752;      // 128*1024
    float* ssg   = ws + 8781824;      // 128*1024
    float* wc    = ws + 8912896;      // 90624
    float* big   = ws + 9003520;      // 16,777,216 (4-batch D2 | gtab+dtab | h5)
    float* gtab  = big;               // up to 8192*256
    float* dtab  = big + 2097152;     // up to 8192*256
    __hip_bfloat16* xch = (__hip_bfloat16*)(ws + 25780736);  // 8192*512 bf16
    __hip_bfloat16* w5h = (__hip_bfloat16*)(ws + 27877888);  // 1024*512 bf16
    float* wft   = ws + 28140032;     // 1024*256 transposed Wf
    float* l5s   = ws + 28402176;     // 64*1024 L5 col sums
    float* l5q   = ws + 28467712;     // 64*1024 L5 col sumsq

    hipMemsetAsync(stats, 0, 65536 * sizeof(float), stream);
    k_transpose<<<32, 256, 0, stream>>>(x, xt1, xx);
    k_prepw_all<<<3426, 256, 0, stream>>>(W1, W2, W3, W4, W5, Wf, wc, w5h, wft);

    const float invMk = 1.f / (float)(BN_ROWS * KNN);

    // ------------- layer 1: C=3, O=64
    {
        float* ss = stats + 0;
        k_mm128<MODE_DIST, false><<<dim3(136, 1, 4), 256, 0, stream>>>(xt1, 3, nullptr, 0, xx, 0, big, nullptr, N_PTS, 3);
        k_select<<<2048, 256, 0, stream>>>(big, idx);
        k_mm128<MODE_GD, false><<<dim3(2, 64, 1), 256, 0, stream>>>(xt1, 3, wc, 3, nullptr, 0, gtab, dtab, 128, 3);
        k_gather<64, 8><<<256, 256, 0, stream>>>(gtab, dtab, idx, hmax, hmin, ss, ss + 4096);
        k_normalize<64, true><<<512, 256, 0, stream>>>(hmax, hmin, ss, ss + 4096, g1, b1, invMk, xc + 0, xch + 0, xx);
    }
    // ------------- layer 2: C=64, O=64
    {
        float* ss = stats + 8192;
        k_mm128<MODE_DIST, true><<<dim3(136, 1, 4), 256, 0, stream>>>(xc + 0, 512, nullptr, 0, xx, 0, big, nullptr, N_PTS, 64);
        k_select<<<2048, 256, 0, stream>>>(big, idx);
        k_mm128<MODE_GD, true><<<dim3(2, 64, 1), 256, 0, stream>>>(xc + 0, 512, wc + 384, 64, nullptr, 0, gtab, dtab, 128, 64);
        k_gather<64, 8><<<256, 256, 0, stream>>>(gtab, dtab, idx, hmax, hmin, ss, ss + 4096);
        k_normalize<64, true><<<512, 256, 0, stream>>>(hmax, hmin, ss, ss + 4096, g2, b2, invMk, xc + 64, xch + 64, xx);
    }
    // ------------- layer 3: C=64, O=128
    {
        float* ss = stats + 16384;
        k_mm128<MODE_DIST, true><<<dim3(136, 1, 4), 256, 0, stream>>>(xc + 64, 512, nullptr, 0, xx, 0, big, nullptr, N_PTS, 64);
        k_select<<<2048, 256, 0, stream>>>(big, idx);
        k_mm128<MODE_GD, true><<<dim3(4, 64, 1), 256, 0, stream>>>(xc + 64, 512, wc + 8576, 64, nullptr, 0, gtab, dtab, 256, 64);
        k_gather<128, 8><<<512, 256, 0, stream>>>(gtab, dtab, idx, hmax, hmin, ss, ss + 8192);
        k_normalize<128, true><<<512, 256, 0, stream>>>(hmax, hmin, ss, ss + 8192, g3, b3, invMk, xc + 128, xch + 128, xx);
    }
    // ------------- layer 4: C=128, O=256
    {
        float* ss = stats + 32768;
        k_mm128<MODE_DIST, true><<<dim3(136, 1, 4), 256, 0, stream>>>(xc + 128, 512, nullptr, 0, xx, 0, big, nullptr, N_PTS, 128);
        k_select<<<2048, 256, 0, stream>>>(big, idx);
        k_mm128<MODE_GD, true><<<dim3(8, 64, 1), 256, 0, stream>>>(xc + 128, 512, wc + 24960, 128, nullptr, 0, gtab, dtab, 512, 128);
        k_gather<256, 8><<<1024, 256, 0, stream>>>(gtab, dtab, idx, hmax, hmin, ss, ss + 16384);
        k_normalize<256, false><<<512, 256, 0, stream>>>(hmax, hmin, ss, ss + 16384, g4, b4, invMk, xc + 256, xch + 256, xx);
    }
    // ------------- layer 5: bf16 MFMA GEMM (+fused stats), seg, final
    {
        k_gemm5<<<dim3(8, 64), 256, 0, stream>>>((const unsigned short*)xch, (const unsigned short*)w5h, big, l5s, l5q);
        k_seg<<<dim3(128, 4), 256, 0, stream>>>(big, l5s, l5q, g5, b5, smax, ssg);
        k_final<<<252, 256, 0, stream>>>(smax, ssg, wft, bfeat, out);
    }
}

// Round 16
// 576.726 us; speedup vs baseline: 1.1563x; 1.0411x over previous
//
#include <hip/hip_runtime.h>
#include <hip/hip_bf16.h>
#include <cstdint>
#include <cstddef>

#define B_SZ   4
#define N_PTS  2048
#define KNN    20
#define BN_ROWS (B_SZ * N_PTS)
#define EPSV   1e-5f
#define SLOPEV 0.2f

#define MODE_GD   0
#define MODE_DIST 1

typedef __attribute__((ext_vector_type(8))) short bf16x8;
typedef __attribute__((ext_vector_type(4))) float f32x4;

// ---------------------------------------------------------------- transpose + xx
__global__ void k_transpose(const float* __restrict__ x, float* __restrict__ xt,
                            float* __restrict__ xx)
{
    int i = blockIdx.x * 256 + threadIdx.x;
    if (i >= BN_ROWS) return;
    int b = i >> 11, n = i & 2047;
    float v0 = x[((b * 3 + 0) << 11) + n];
    float v1 = x[((b * 3 + 1) << 11) + n];
    float v2 = x[((b * 3 + 2) << 11) + n];
    xt[i * 3 + 0] = v0; xt[i * 3 + 1] = v1; xt[i * 3 + 2] = v2;
    xx[i] = fmaf(v0, v0, fmaf(v1, v1, v2 * v2));
}

// ---------------------------------------------------------------- batched weight prep
__global__ void k_prepw_all(const float* __restrict__ W1, const float* __restrict__ W2,
                            const float* __restrict__ W3, const float* __restrict__ W4,
                            const float* __restrict__ W5, const float* __restrict__ Wf,
                            float* __restrict__ wc, __hip_bfloat16* __restrict__ w5h,
                            float* __restrict__ wft)
{
    int i = blockIdx.x * 256 + threadIdx.x;
    if (i >= 876928) return;
    if (i >= 614784) {                      // Wf transpose
        int e = i - 614784;                 // e = o*1024 + f
        int o = e >> 10, f = e & 1023;
        wft[f * 256 + o] = Wf[e];
        return;
    }
    if (i >= 90496) {                       // W5 (1024x512) -> bf16
        int e = i - 90496;
        w5h[e] = __float2bfloat16(W5[e]);
        return;
    }
    const float* W; int O, C, off;
    if      (i < 384)   { W = W1; O = 64;  C = 3;   off = 0; }
    else if (i < 8576)  { W = W2; O = 64;  C = 64;  off = 384; }
    else if (i < 24960) { W = W3; O = 128; C = 64;  off = 8576; }
    else                { W = W4; O = 256; C = 128; off = 24960; }
    int e = i - off, j = e / C, c = e - j * C;
    float v;
    if (j < O) v = W[j * 2 * C + c];
    else { int jo = j - O; v = W[jo * 2 * C + C + c] - W[jo * 2 * C + c]; }
    wc[i] = v;
}

// ---------------------------------------------------------------- GEMM core
// MODE_GD  : 128x64 tile. C = A(MxK) @ Bm(NnxK)^T, grid (Nn/64, M/128).
// MODE_DIST: 128x128 SYMMETRIC tile, grid (136, 1, 4). 120 off-diagonal pairs
//   first, 16 diagonal tiles last (cheap tail — no mirror epilogue). Diagonal
//   forced to exact 0; D2 bitwise identical to previous rounds.
template<int MODE, bool VEC>
__launch_bounds__(256)
__global__ void k_mm128(const float* __restrict__ A, int lda,
                        const float* __restrict__ Bm, int ldb,
                        const float* __restrict__ xx, int b0,
                        float* __restrict__ C1, float* __restrict__ C2,
                        int Nn, int Kd)
{
    constexpr int LDA_ = 132;     // 128 + 4 pad
    constexpr int LDB_ = (MODE == MODE_DIST) ? 132 : 68;
    constexpr int SMEMF = 32 * LDA_ + 32 * LDB_;   // DIST: 8448, GD: 6400
    __shared__ float smem[SMEMF];
    float* As = smem;
    float* Bs = smem + 32 * LDA_;
    float* T  = smem;             // DIST mirror transpose: 64 x 132 = 8448 == SMEMF
    const int tid = threadIdx.x;
    const int tx  = tid & 15;
    const int ty  = tid >> 4;

    int m0, n0;
    if constexpr (MODE == MODE_DIST) {
        int t = blockIdx.x;
        int it, jt;
        if (t < 120) {                     // off-diagonal pairs first
            int i = 0;
            for (; i < 15; ++i) { int cnt = 15 - i; if (t < cnt) break; t -= cnt; }
            it = i; jt = i + 1 + t;
        } else {                           // 16 diagonal tiles last (no mirror)
            it = jt = t - 120;
        }
        m0 = it * 128;
        n0 = jt * 128;
    } else {
        m0 = blockIdx.y * 128;
        n0 = blockIdx.x * 64;
    }

    const float* Ab;
    const float* Bb;
    int ldbe;
    if constexpr (MODE == MODE_DIST) {
        const int b = b0 + blockIdx.z;
        Ab = A + (size_t)b * N_PTS * lda;
        Bb = Ab;
        ldbe = lda;
    } else {
        Ab = A; Bb = Bm; ldbe = ldb;
    }

    constexpr int NJH = (MODE == MODE_DIST) ? 2 : 1;
    float acc[2][NJH][4][4] = {};

    for (int k0 = 0; k0 < Kd; k0 += 32) {
        #pragma unroll
        for (int r = 0; r < 4; ++r) {            // A: 128 rows x 32 k
            int e = r * 256 + tid, row = e >> 3, kq = e & 7;
            if constexpr (VEC) {
                float4 v = *(const float4*)&Ab[(size_t)(m0 + row) * lda + k0 + kq * 4];
                As[(kq * 4 + 0) * LDA_ + row] = v.x;
                As[(kq * 4 + 1) * LDA_ + row] = v.y;
                As[(kq * 4 + 2) * LDA_ + row] = v.z;
                As[(kq * 4 + 3) * LDA_ + row] = v.w;
            } else {
                #pragma unroll
                for (int j = 0; j < 4; ++j) {
                    int kg = k0 + kq * 4 + j;
                    As[(kq * 4 + j) * LDA_ + row] =
                        (kg < Kd) ? Ab[(size_t)(m0 + row) * lda + kg] : 0.f;
                }
            }
        }
        constexpr int BR = (MODE == MODE_DIST) ? 4 : 2;
        #pragma unroll
        for (int r = 0; r < BR; ++r) {
            int e = r * 256 + tid, row = e >> 3, kq = e & 7;
            if constexpr (VEC) {
                float4 v = *(const float4*)&Bb[(size_t)(n0 + row) * ldbe + k0 + kq * 4];
                Bs[(kq * 4 + 0) * LDB_ + row] = v.x;
                Bs[(kq * 4 + 1) * LDB_ + row] = v.y;
                Bs[(kq * 4 + 2) * LDB_ + row] = v.z;
                Bs[(kq * 4 + 3) * LDB_ + row] = v.w;
            } else {
                #pragma unroll
                for (int j = 0; j < 4; ++j) {
                    int kg = k0 + kq * 4 + j;
                    Bs[(kq * 4 + j) * LDB_ + row] =
                        (kg < Kd) ? Bb[(size_t)(n0 + row) * ldbe + kg] : 0.f;
                }
            }
        }
        __syncthreads();

        int klen = Kd - k0; if (klen > 32) klen = 32;
        #pragma unroll 8
        for (int kk = 0; kk < klen; ++kk) {
            float4 a0 = *(const float4*)&As[kk * LDA_ + ty * 4];
            float4 a1 = *(const float4*)&As[kk * LDA_ + 64 + ty * 4];
            float av[2][4] = {{a0.x,a0.y,a0.z,a0.w},{a1.x,a1.y,a1.z,a1.w}};
            if constexpr (MODE == MODE_DIST) {
                float4 b0q = *(const float4*)&Bs[kk * LDB_ + tx * 4];
                float4 b1q = *(const float4*)&Bs[kk * LDB_ + 64 + tx * 4];
                float bw[2][4] = {{b0q.x,b0q.y,b0q.z,b0q.w},{b1q.x,b1q.y,b1q.z,b1q.w}};
                #pragma unroll
                for (int ih = 0; ih < 2; ++ih)
                    #pragma unroll
                    for (int jh = 0; jh < 2; ++jh)
                        #pragma unroll
                        for (int ii = 0; ii < 4; ++ii)
                            #pragma unroll
                            for (int jj = 0; jj < 4; ++jj)
                                acc[ih][jh][ii][jj] = fmaf(av[ih][ii], bw[jh][jj], acc[ih][jh][ii][jj]);
            } else {
                float4 bq = *(const float4*)&Bs[kk * LDB_ + tx * 4];
                float bw[4] = {bq.x, bq.y, bq.z, bq.w};
                #pragma unroll
                for (int ih = 0; ih < 2; ++ih)
                    #pragma unroll
                    for (int ii = 0; ii < 4; ++ii)
                        #pragma unroll
                        for (int jj = 0; jj < 4; ++jj)
                            acc[ih][0][ii][jj] = fmaf(av[ih][ii], bw[jj], acc[ih][0][ii][jj]);
            }
        }
        __syncthreads();
    }

    if constexpr (MODE == MODE_DIST) {
        const float* xxb = xx + (b0 + blockIdx.z) * N_PTS;
        float xj[2][4];
        #pragma unroll
        for (int jh = 0; jh < 2; ++jh) {
            float4 v = *(const float4*)&xxb[n0 + jh * 64 + tx * 4];
            xj[jh][0] = v.x; xj[jh][1] = v.y; xj[jh][2] = v.z; xj[jh][3] = v.w;
        }
        float xiv[2][4];
        #pragma unroll
        for (int ih = 0; ih < 2; ++ih)
            #pragma unroll
            for (int i = 0; i < 4; ++i)
                xiv[ih][i] = xxb[m0 + ih * 64 + ty * 4 + i];
        const bool diag = (m0 == n0);
        const size_t zoff = (size_t)blockIdx.z * N_PTS;

        #pragma unroll
        for (int ih = 0; ih < 2; ++ih)
            #pragma unroll
            for (int i = 0; i < 4; ++i) {
                int gi = m0 + ih * 64 + ty * 4 + i;
                float xi = xiv[ih][i];
                size_t base = (zoff + gi) * N_PTS;
                #pragma unroll
                for (int jh = 0; jh < 2; ++jh) {
                    int gj = n0 + jh * 64 + tx * 4;
                    float4 v;
                    v.x = 2.f * acc[ih][jh][i][0] - xi - xj[jh][0];
                    v.y = 2.f * acc[ih][jh][i][1] - xi - xj[jh][1];
                    v.z = 2.f * acc[ih][jh][i][2] - xi - xj[jh][2];
                    v.w = 2.f * acc[ih][jh][i][3] - xi - xj[jh][3];
                    if (diag) {
                        if (gi == gj + 0) v.x = 0.f;
                        if (gi == gj + 1) v.y = 0.f;
                        if (gi == gj + 2) v.z = 0.f;
                        if (gi == gj + 3) v.w = 0.f;
                    }
                    *(float4*)&C1[base + gj] = v;
                }
            }

        if (!diag) {
            #pragma unroll
            for (int jh = 0; jh < 2; ++jh) {
                #pragma unroll
                for (int c = 0; c < 4; ++c) {
                    float xjc = xj[jh][c];
                    #pragma unroll
                    for (int ih = 0; ih < 2; ++ih) {
                        float4 tv;
                        tv.x = 2.f * acc[ih][jh][0][c] - xjc - xiv[ih][0];
                        tv.y = 2.f * acc[ih][jh][1][c] - xjc - xiv[ih][1];
                        tv.z = 2.f * acc[ih][jh][2][c] - xjc - xiv[ih][2];
                        tv.w = 2.f * acc[ih][jh][3][c] - xjc - xiv[ih][3];
                        *(float4*)&T[(tx * 4 + c) * LDA_ + ih * 64 + ty * 4] = tv;
                    }
                }
                __syncthreads();
                #pragma unroll
                for (int r = 0; r < 8; ++r) {
                    int e = r * 256 + tid;
                    int jr = e >> 5, c4 = e & 31;
                    float4 tv = *(const float4*)&T[jr * LDA_ + c4 * 4];
                    *(float4*)&C1[(zoff + n0 + jh * 64 + jr) * N_PTS + m0 + c4 * 4] = tv;
                }
                __syncthreads();
            }
        }
    } else {  // MODE_GD
        const int Oo = Nn >> 1;
        #pragma unroll
        for (int ih = 0; ih < 2; ++ih)
            #pragma unroll
            for (int i = 0; i < 4; ++i) {
                int row = m0 + ih * 64 + ty * 4 + i;
                int colg = n0 + tx * 4;
                float4 v = make_float4(acc[ih][0][i][0], acc[ih][0][i][1],
                                       acc[ih][0][i][2], acc[ih][0][i][3]);
                if (colg < Oo) *(float4*)&C1[(size_t)row * Oo + colg] = v;
                else           *(float4*)&C2[(size_t)row * Oo + colg - Oo] = v;
            }
    }
}

// ---------------------------------------------------------------- bf16 MFMA GEMM (layer 5)
__launch_bounds__(256)
__global__ void k_gemm5(const unsigned short* __restrict__ Ah,
                        const unsigned short* __restrict__ Bh,
                        float* __restrict__ Cf,
                        float* __restrict__ ssum, float* __restrict__ ssumsq)
{
    constexpr int LDA = 72;
    __shared__ unsigned short As[128 * LDA];
    __shared__ unsigned short Bs[128 * LDA];
    const int tid  = threadIdx.x;
    const int lane = tid & 63;
    const int w    = tid >> 6;
    const int wr   = w >> 1, wcl = w & 1;
    const int quad = lane >> 4;
    const int l16  = lane & 15;
    const int m0 = blockIdx.y * 128;
    const int n0 = blockIdx.x * 128;

    f32x4 acc[4][4] = {};

    for (int k0 = 0; k0 < 512; k0 += 64) {
        #pragma unroll
        for (int r = 0; r < 4; ++r) {
            int e = r * 256 + tid, row = e >> 3, kq = e & 7;
            *(uint4*)&As[row * LDA + kq * 8] =
                *(const uint4*)&Ah[(size_t)(m0 + row) * 512 + k0 + kq * 8];
        }
        #pragma unroll
        for (int r = 0; r < 4; ++r) {
            int e = r * 256 + tid, row = e >> 3, kq = e & 7;
            *(uint4*)&Bs[row * LDA + kq * 8] =
                *(const uint4*)&Bh[(size_t)(n0 + row) * 512 + k0 + kq * 8];
        }
        __syncthreads();
        #pragma unroll
        for (int kk = 0; kk < 64; kk += 32) {
            bf16x8 af[4], bfr[4];
            #pragma unroll
            for (int i = 0; i < 4; ++i)
                af[i] = *(const bf16x8*)&As[(wr * 64 + i * 16 + l16) * LDA + kk + quad * 8];
            #pragma unroll
            for (int j = 0; j < 4; ++j)
                bfr[j] = *(const bf16x8*)&Bs[(wcl * 64 + j * 16 + l16) * LDA + kk + quad * 8];
            #pragma unroll
            for (int i = 0; i < 4; ++i)
                #pragma unroll
                for (int j = 0; j < 4; ++j)
                    acc[i][j] = __builtin_amdgcn_mfma_f32_16x16x32_bf16(af[i], bfr[j], acc[i][j], 0, 0, 0);
        }
        __syncthreads();
    }

    #pragma unroll
    for (int i = 0; i < 4; ++i) {
        int rbase = m0 + wr * 64 + i * 16 + quad * 4;
        #pragma unroll
        for (int j = 0; j < 4; ++j) {
            int col = n0 + wcl * 64 + j * 16 + l16;
            #pragma unroll
            for (int r = 0; r < 4; ++r)
                Cf[(size_t)(rbase + r) * 1024 + col] = acc[i][j][r];
        }
    }

    float* sredS = (float*)As;
    float* sredQ = (float*)Bs;
    #pragma unroll
    for (int j = 0; j < 4; ++j) {
        float s = 0.f, q = 0.f;
        #pragma unroll
        for (int i = 0; i < 4; ++i)
            #pragma unroll
            for (int r = 0; r < 4; ++r) {
                float v = acc[i][j][r];
                s += v; q = fmaf(v, v, q);
            }
        int coll = wcl * 64 + j * 16 + l16;
        int slot = wr * 4 + quad;
        sredS[coll * 8 + slot] = s;
        sredQ[coll * 8 + slot] = q;
    }
    __syncthreads();
    if (tid < 128) {
        float s = 0.f, q = 0.f;
        #pragma unroll
        for (int t = 0; t < 8; ++t) { s += sredS[tid * 8 + t]; q += sredQ[tid * 8 + t]; }
        ssum  [blockIdx.y * 1024 + n0 + tid] = s;
        ssumsq[blockIdx.y * 1024 + n0 + tid] = q;
    }
}

// ---------------------------------------------------------------- top-20 select (all 4 batches)
// Ballot-count bisection. CRITICAL: every loop touching key[] is FULLY
// UNROLLED (constant indices) so key[32] lives in VGPRs. Round-15's tie-fill
// loop had a dynamic trip count (`&& base < KNN`) -> runtime-indexed key[e]
// -> scratch demotion (VGPR_Count=24) -> every bisection iteration re-read
// 32 keys from memory (~1.8 GB L2 traffic = the measured 54.7us).
__launch_bounds__(256)
__global__ void k_select(const float* __restrict__ D2, int* __restrict__ idx_out)
{
    const int lane = threadIdx.x & 63;
    const int w    = threadIdx.x >> 6;
    const int qloc = blockIdx.x * 4 + w;          // 0..8191
    const float* row = D2 + (size_t)qloc * N_PTS;

    unsigned key[32];
    #pragma unroll
    for (int c = 0; c < 8; ++c) {
        float4 v = *(const float4*)&row[c * 256 + lane * 4];
        float vv[4] = {v.x, v.y, v.z, v.w};
        #pragma unroll
        for (int r = 0; r < 4; ++r) {
            unsigned u = __float_as_uint(vv[r]);
            key[c * 4 + r] = ((int)u >= 0) ? (u | 0x80000000u) : ~u;
        }
    }

    // bisection: T = smallest m with #{key > m} < 20
    unsigned lo = 0u, hi = 0xFFFFFFFFu;
    while (lo < hi) {
        unsigned mid = lo + ((hi - lo) >> 1);
        int cnt = 0;
        #pragma unroll
        for (int e = 0; e < 32; ++e)
            cnt += __popcll(__ballot(key[e] > mid));
        if (cnt < KNN) hi = mid; else lo = mid + 1;
    }
    const unsigned T = lo;

    int* outp = idx_out + (size_t)qloc * KNN;
    const unsigned long long ltmask = (lane == 0) ? 0ull : (~0ull >> (64 - lane));
    int base = 0;
    #pragma unroll
    for (int e = 0; e < 32; ++e) {
        bool p = key[e] > T;
        unsigned long long m = __ballot(p);
        if (p) {
            int pos = base + __popcll(m & ltmask);
            outp[pos] = (e >> 2) * 256 + lane * 4 + (e & 3);
        }
        base += __popcll(m);
    }
    // tie-fill: fully unrolled (no dynamic trip count!), writes guarded by pos<KNN
    #pragma unroll
    for (int e = 0; e < 32; ++e) {
        bool p = key[e] == T;
        unsigned long long m = __ballot(p);
        if (p) {
            int pos = base + __popcll(m & ltmask);
            if (pos < KNN) outp[pos] = (e >> 2) * 256 + lane * 4 + (e & 3);
        }
        base += __popcll(m);
    }
}

// ---------------------------------------------------------------- gather + stats
template<int O, int NSEQ>
__launch_bounds__(256)
__global__ void k_gather(const float* __restrict__ gtab, const float* __restrict__ dtab,
                         const int* __restrict__ idx,
                         float* __restrict__ hmax, float* __restrict__ hmin,
                         float* __restrict__ ssum, float* __restrict__ ssumsq)
{
    constexpr int NPB = 256 / O;
    const int grp = threadIdx.x / O;
    const int o   = threadIdx.x & (O - 1);
    float accS = 0.f, accS2 = 0.f;
    const int rowsPerBlock = NPB * NSEQ;
    const int batch = blockIdx.x & 3;
    const int chunk = blockIdx.x >> 2;
    const int bbase = batch << 11;
    for (int s = 0; s < NSEQ; ++s) {
        int row = bbase + chunk * rowsPerBlock + s * NPB + grp;
        const int* ip = idx + (size_t)row * KNN;
        float gmax = -INFINITY, gmin = INFINITY, gs = 0.f, gs2 = 0.f;
        for (int k = 0; k < KNN; ++k) {
            int nb = ip[k];
            float v = gtab[(size_t)(bbase + nb) * O + o];
            gmax = fmaxf(gmax, v);
            gmin = fminf(gmin, v);
            gs  += v;
            gs2  = fmaf(v, v, gs2);
        }
        float d = dtab[(size_t)row * O + o];
        hmax[(size_t)row * O + o] = gmax + d;
        hmin[(size_t)row * O + o] = gmin + d;
        accS  += gs + (float)KNN * d;
        accS2 += gs2 + 2.f * d * gs + (float)KNN * d * d;
    }
    int bank = blockIdx.x & 63;
    atomicAdd(&ssum[bank * O + o], accS);
    atomicAdd(&ssumsq[bank * O + o], accS2);
}

// ---------------------------------------------------------------- normalize (+BN finalize, +xx, +bf16 mirror)
template<int O, bool WRITE_XX>
__launch_bounds__(256)
__global__ void k_normalize(const float* __restrict__ hmax, const float* __restrict__ hmin,
                            const float* __restrict__ ssum, const float* __restrict__ ssumsq,
                            const float* __restrict__ gamma, const float* __restrict__ beta,
                            float invM, float* __restrict__ xcs,
                            __hip_bfloat16* __restrict__ xch, float* __restrict__ xx)
{
    const int tid = threadIdx.x;
    const int o   = tid & (O - 1);
    float s = 0.f, s2 = 0.f;
    #pragma unroll 8
    for (int bk = 0; bk < 64; ++bk) { s += ssum[bk * O + o]; s2 += ssumsq[bk * O + o]; }
    float mean = s * invM;
    float var  = fmaf(-mean, mean, s2 * invM);
    float sc   = gamma[o] * rsqrtf(var + EPSV);
    float sh   = beta[o] - mean * sc;

    constexpr int R = 256 / O;
    const int rloc = tid / O;
    __shared__ float part[4];
    const int ngroups = BN_ROWS / R;
    for (int gidx = blockIdx.x; gidx < ngroups; gidx += gridDim.x) {
        int row = gidx * R + rloc;
        size_t i = (size_t)row * O + o;
        float h = (sc >= 0.f) ? hmax[i] : hmin[i];
        float y = fmaf(h, sc, sh);
        y = (y >= 0.f) ? y : SLOPEV * y;
        xcs[(size_t)row * 512 + o] = y;
        xch[(size_t)row * 512 + o] = __float2bfloat16(y);
        if constexpr (WRITE_XX) {
            float p = y * y;
            #pragma unroll
            for (int sft = 32; sft >= 1; sft >>= 1) p += __shfl_xor(p, sft, 64);
            if constexpr (O == 64) {
                if ((tid & 63) == 0) xx[row] = p;
            } else {
                if ((tid & 63) == 0) part[tid >> 6] = p;
                __syncthreads();
                if constexpr (O == 128) {
                    if (tid < 2) xx[gidx * R + tid] = part[2 * tid] + part[2 * tid + 1];
                } else {
                    if (tid == 0) xx[gidx * R] = (part[0] + part[1]) + (part[2] + part[3]);
                }
                __syncthreads();
            }
        }
    }
}

// ---------------------------------------------------------------- seg max/sum (+finalize, 64 banks)
__global__ void k_seg(const float* __restrict__ h,
                      const float* __restrict__ ssum, const float* __restrict__ ssumsq,
                      const float* __restrict__ gamma, const float* __restrict__ beta,
                      float* __restrict__ smax, float* __restrict__ ssumseg)
{
    int f = blockIdx.y * 256 + threadIdx.x;
    float s = 0.f, s2 = 0.f;
    #pragma unroll 8
    for (int bk = 0; bk < 64; ++bk) { s += ssum[bk * 1024 + f]; s2 += ssumsq[bk * 1024 + f]; }
    const float invM = 1.f / (float)BN_ROWS;
    float mean = s * invM;
    float var  = fmaf(-mean, mean, s2 * invM);
    float sc   = gamma[f] * rsqrtf(var + EPSV);
    float sh   = beta[f] - mean * sc;

    int seg = blockIdx.x;
    float mx = -INFINITY, sm = 0.f;
    int n0 = seg * 64;
    for (int i = 0; i < 64; ++i) {
        float v = fmaf(h[(size_t)(n0 + i) * 1024 + f], sc, sh);
        v = (v >= 0.f) ? v : SLOPEV * v;
        mx = fmaxf(mx, v); sm += v;
    }
    smax[(size_t)seg * 1024 + f]    = mx;
    ssumseg[(size_t)seg * 1024 + f] = sm;
}

// ---------------------------------------------------------------- final projection (+bin combine)
__launch_bounds__(256)
__global__ void k_final(const float* __restrict__ smax, const float* __restrict__ ssg,
                        const float* __restrict__ Wft, const float* __restrict__ bfeat,
                        float* __restrict__ out)
{
    __shared__ float row[1024];
    __shared__ float part[1024];
    const int tid = threadIdx.x;
    int sb = blockIdx.x;             // s*4 + b, s in 0..62
    int s = sb >> 2, b = sb & 3;
    int nb = (s == 0) ? 1 : (s < 3) ? 2 : (s < 7) ? 4 : (s < 15) ? 8 : (s < 31) ? 16 : 32;
    int idxL = s - (nb - 1);
    int segc = 32 / nb;
    int seg0 = b * 32 + idxL * segc;
    float inv = 1.f / (float)(64 * segc);
    for (int c = tid; c < 1024; c += 256) {
        float mx = -INFINITY, sm = 0.f;
        for (int t = 0; t < segc; ++t) {
            mx = fmaxf(mx, smax[(size_t)(seg0 + t) * 1024 + c]);
            sm += ssg[(size_t)(seg0 + t) * 1024 + c];
        }
        row[c] = mx + sm * inv;
    }
    __syncthreads();

    const int lane = tid & 63;
    const int w    = tid >> 6;
    const float* rw = row + w * 256;
    const float* wp = Wft + (size_t)(w * 256) * 256 + lane * 4;
    float4 a0 = {0,0,0,0}, a1 = {0,0,0,0}, a2 = {0,0,0,0}, a3 = {0,0,0,0};
    for (int f = 0; f < 256; f += 4) {
        float r0 = rw[f + 0], r1 = rw[f + 1], r2 = rw[f + 2], r3 = rw[f + 3];
        float4 w0 = *(const float4*)&wp[(size_t)(f + 0) * 256];
        float4 w1 = *(const float4*)&wp[(size_t)(f + 1) * 256];
        float4 w2 = *(const float4*)&wp[(size_t)(f + 2) * 256];
        float4 w3 = *(const float4*)&wp[(size_t)(f + 3) * 256];
        a0.x = fmaf(r0, w0.x, a0.x); a0.y = fmaf(r0, w0.y, a0.y);
        a0.z = fmaf(r0, w0.z, a0.z); a0.w = fmaf(r0, w0.w, a0.w);
        a1.x = fmaf(r1, w1.x, a1.x); a1.y = fmaf(r1, w1.y, a1.y);
        a1.z = fmaf(r1, w1.z, a1.z); a1.w = fmaf(r1, w1.w, a1.w);
        a2.x = fmaf(r2, w2.x, a2.x); a2.y = fmaf(r2, w2.y, a2.y);
        a2.z = fmaf(r2, w2.z, a2.z); a2.w = fmaf(r2, w2.w, a2.w);
        a3.x = fmaf(r3, w3.x, a3.x); a3.y = fmaf(r3, w3.y, a3.y);
        a3.z = fmaf(r3, w3.z, a3.z); a3.w = fmaf(r3, w3.w, a3.w);
    }
    float4 a;
    a.x = (a0.x + a1.x) + (a2.x + a3.x);
    a.y = (a0.y + a1.y) + (a2.y + a3.y);
    a.z = (a0.z + a1.z) + (a2.z + a3.z);
    a.w = (a0.w + a1.w) + (a2.w + a3.w);
    *(float4*)&part[w * 256 + lane * 4] = a;
    __syncthreads();
    int o = tid;
    float acc = (part[o] + part[256 + o]) + (part[512 + o] + part[768 + o]);
    out[(size_t)sb * 256 + o] = acc + bfeat[o];
}

// ================================================================ launch
extern "C" void kernel_launch(void* const* d_in, const int* in_sizes, int n_in,
                              void* d_out, int out_size, void* d_ws, size_t ws_size,
                              hipStream_t stream)
{
    const float* x  = (const float*)d_in[0];
    const float* W1 = (const float*)d_in[1];
    const float* g1 = (const float*)d_in[2];
    const float* b1 = (const float*)d_in[3];
    const float* W2 = (const float*)d_in[4];
    const float* g2 = (const float*)d_in[5];
    const float* b2 = (const float*)d_in[6];
    const float* W3 = (const float*)d_in[7];
    const float* g3 = (const float*)d_in[8];
    const float* b3 = (const float*)d_in[9];
    const float* W4 = (const float*)d_in[10];
    const float* g4 = (const float*)d_in[11];
    const float* b4 = (const float*)d_in[12];
    const float* W5 = (const float*)d_in[13];
    const float* g5 = (const float*)d_in[14];
    const float* b5 = (const float*)d_in[15];
    const float* Wf = (const float*)d_in[16];
    const float* bfeat = (const float*)d_in[17];
    float* out = (float*)d_out;
    float* ws  = (float*)d_ws;

    // workspace layout (floats), total 28,533,248 = 114.1 MB (ws_size ~268 MB)
    float* xt1   = ws + 0;            // 24576
    int*   idx   = (int*)(ws + 24576);// 163840
    float* xx    = ws + 188416;       // 8192
    float* xc    = ws + 196608;       // 8192*512
    float* hmax  = ws + 4390912;      // 8192*256
    float* hmin  = ws + 6488064;      // 8192*256
    float* stats = ws + 8585216;      // 65536 (L1@0 L2@8192 L3@16384 L4@32768)
    float* smax  = ws + 8650752;      // 128*1024
    float* ssg   = ws + 8781824;      // 128*1024
    float* wc    = ws + 8912896;      // 90624
    float* big   = ws + 9003520;      // 16,777,216 (4-batch D2 | gtab+dtab | h5)
    float* gtab  = big;               // up to 8192*256
    float* dtab  = big + 2097152;     // up to 8192*256
    __hip_bfloat16* xch = (__hip_bfloat16*)(ws + 25780736);  // 8192*512 bf16
    __hip_bfloat16* w5h = (__hip_bfloat16*)(ws + 27877888);  // 1024*512 bf16
    float* wft   = ws + 28140032;     // 1024*256 transposed Wf
    float* l5s   = ws + 28402176;     // 64*1024 L5 col sums
    float* l5q   = ws + 28467712;     // 64*1024 L5 col sumsq

    hipMemsetAsync(stats, 0, 65536 * sizeof(float), stream);
    k_transpose<<<32, 256, 0, stream>>>(x, xt1, xx);
    k_prepw_all<<<3426, 256, 0, stream>>>(W1, W2, W3, W4, W5, Wf, wc, w5h, wft);

    const float invMk = 1.f / (float)(BN_ROWS * KNN);

    // ------------- layer 1: C=3, O=64
    {
        float* ss = stats + 0;
        k_mm128<MODE_DIST, false><<<dim3(136, 1, 4), 256, 0, stream>>>(xt1, 3, nullptr, 0, xx, 0, big, nullptr, N_PTS, 3);
        k_select<<<2048, 256, 0, stream>>>(big, idx);
        k_mm128<MODE_GD, false><<<dim3(2, 64, 1), 256, 0, stream>>>(xt1, 3, wc, 3, nullptr, 0, gtab, dtab, 128, 3);
        k_gather<64, 8><<<256, 256, 0, stream>>>(gtab, dtab, idx, hmax, hmin, ss, ss + 4096);
        k_normalize<64, true><<<512, 256, 0, stream>>>(hmax, hmin, ss, ss + 4096, g1, b1, invMk, xc + 0, xch + 0, xx);
    }
    // ------------- layer 2: C=64, O=64
    {
        float* ss = stats + 8192;
        k_mm128<MODE_DIST, true><<<dim3(136, 1, 4), 256, 0, stream>>>(xc + 0, 512, nullptr, 0, xx, 0, big, nullptr, N_PTS, 64);
        k_select<<<2048, 256, 0, stream>>>(big, idx);
        k_mm128<MODE_GD, true><<<dim3(2, 64, 1), 256, 0, stream>>>(xc + 0, 512, wc + 384, 64, nullptr, 0, gtab, dtab, 128, 64);
        k_gather<64, 8><<<256, 256, 0, stream>>>(gtab, dtab, idx, hmax, hmin, ss, ss + 4096);
        k_normalize<64, true><<<512, 256, 0, stream>>>(hmax, hmin, ss, ss + 4096, g2, b2, invMk, xc + 64, xch + 64, xx);
    }
    // ------------- layer 3: C=64, O=128
    {
        float* ss = stats + 16384;
        k_mm128<MODE_DIST, true><<<dim3(136, 1, 4), 256, 0, stream>>>(xc + 64, 512, nullptr, 0, xx, 0, big, nullptr, N_PTS, 64);
        k_select<<<2048, 256, 0, stream>>>(big, idx);
        k_mm128<MODE_GD, true><<<dim3(4, 64, 1), 256, 0, stream>>>(xc + 64, 512, wc + 8576, 64, nullptr, 0, gtab, dtab, 256, 64);
        k_gather<128, 8><<<512, 256, 0, stream>>>(gtab, dtab, idx, hmax, hmin, ss, ss + 8192);
        k_normalize<128, true><<<512, 256, 0, stream>>>(hmax, hmin, ss, ss + 8192, g3, b3, invMk, xc + 128, xch + 128, xx);
    }
    // ------------- layer 4: C=128, O=256
    {
        float* ss = stats + 32768;
        k_mm128<MODE_DIST, true><<<dim3(136, 1, 4), 256, 0, stream>>>(xc + 128, 512, nullptr, 0, xx, 0, big, nullptr, N_PTS, 128);
        k_select<<<2048, 256, 0, stream>>>(big, idx);
        k_mm128<MODE_GD, true><<<dim3(8, 64, 1), 256, 0, stream>>>(xc + 128, 512, wc + 24960, 128, nullptr, 0, gtab, dtab, 512, 128);
        k_gather<256, 8><<<1024, 256, 0, stream>>>(gtab, dtab, idx, hmax, hmin, ss, ss + 16384);
        k_normalize<256, false><<<512, 256, 0, stream>>>(hmax, hmin, ss, ss + 16384, g4, b4, invMk, xc + 256, xch + 256, xx);
    }
    // ------------- layer 5: bf16 MFMA GEMM (+fused stats), seg, final
    {
        k_gemm5<<<dim3(8, 64), 256, 0, stream>>>((const unsigned short*)xch, (const unsigned short*)w5h, big, l5s, l5q);
        k_seg<<<dim3(128, 4), 256, 0, stream>>>(big, l5s, l5q, g5, b5, smax, ssg);
        k_final<<<252, 256, 0, stream>>>(smax, ssg, wft, bfeat, out);
    }
}